// Round 5
// baseline (601.557 us; speedup 1.0000x reference)
//
#include <hip/hip_runtime.h>

// Problem constants
constexpr int BATCH = 8;
constexpr int NPT   = 8192;   // N points
constexpr int NSMP  = 2048;   // S sampled points
constexpr int D1C   = 128;    // skip feature channels
constexpr int D2C   = 256;    // sampled feature channels
constexpr int CIN   = 384;    // D1C + D2C
constexpr int C1    = 256;    // layer-1 out channels
constexpr int C2    = 128;    // layer-2 out channels
constexpr int BN_TOTAL = BATCH * NPT;  // 65536 rows

// Multi-wave GEMM tiling: 4 waves (256 thr), 128x128 tile, BK=32 (m97 structure)
constexpr int BM = 128, BK = 32;
constexpr int NRB = BN_TOTAL / BM;   // 512 row-blocks
constexpr int NRW = NRB * 2;         // partial slots: 2 row-waves per block

typedef __bf16 bf16x8 __attribute__((ext_vector_type(8)));
typedef short  s16x8  __attribute__((ext_vector_type(8)));
typedef float  f32x4  __attribute__((ext_vector_type(4)));
typedef unsigned short u16x4 __attribute__((ext_vector_type(4)));

__device__ __forceinline__ unsigned short f2bf(float x) {
  unsigned u = __builtin_bit_cast(unsigned, x);
  u += 0x7fffu + ((u >> 16) & 1u);   // round-to-nearest-even
  return (unsigned short)(u >> 16);
}
__device__ __forceinline__ float bf2f(unsigned short h) {
  return __builtin_bit_cast(float, (unsigned)h << 16);
}

// async global -> LDS, 16 B per lane; lds dest wave-uniform base + lane*16
__device__ __forceinline__ void gld_lds16(const void* g, void* l) {
  __builtin_amdgcn_global_load_lds(
      (const __attribute__((address_space(1))) void*)g,
      (__attribute__((address_space(3))) void*)l, 16, 0, 0);
}

// ---------------------------------------------------------------------------
// prep_all: fused transpose(sfeat->sfeatT) + skip->featB + W casts + spos pack
// + pipeline counter zeroing. Role selected by block-index range.
// Launch-count is the dominant non-knn cost (~7-15us/node measured R0->R1):
// 11 nodes -> 5 this round.
// ---------------------------------------------------------------------------
constexpr int PT_T = (NSMP / 32) * (D2C / 32) * BATCH;  // 4096 transpose blocks
constexpr int PT_S = (NPT / 32) * (D1C / 32) * BATCH;   // 8192 skip blocks
constexpr int PT_M = (C1 * CIN + 255) / 256;            // 384 misc blocks

__global__ __launch_bounds__(256) void prep_all(
    const float* __restrict__ sfeat, float* __restrict__ sfeatT,
    const float* __restrict__ skip, unsigned short* __restrict__ featB,
    const float* __restrict__ spos, float* __restrict__ sposI,
    float4* __restrict__ qs4,
    const float* __restrict__ W1, unsigned short* __restrict__ W1h,
    const float* __restrict__ W2, unsigned short* __restrict__ W2h,
    int* __restrict__ ctrs) {
  __shared__ float tile[32][33];
  int bid = blockIdx.x, tid = threadIdx.x;
  int tx = tid & 31, ty = tid >> 5;
  if (bid < PT_T) {
    // transpose sfeat [B, D2C, NSMP] -> sfeatT [B, NSMP, D2C]
    int z = bid >> 9;           // 512 blocks per batch
    int r = bid & 511;
    int c0 = (r & 63) * 32;     // over NSMP
    int r0 = (r >> 6) * 32;     // over D2C
    const float* inb = sfeat + (size_t)z * D2C * NSMP;
    float* outb = sfeatT + (size_t)z * NSMP * D2C;
#pragma unroll
    for (int i = 0; i < 32; i += 8)
      tile[ty + i][tx] = inb[(size_t)(r0 + ty + i) * NSMP + c0 + tx];
    __syncthreads();
#pragma unroll
    for (int i = 0; i < 32; i += 8)
      outb[(size_t)(c0 + ty + i) * D2C + r0 + tx] = tile[tx][ty + i];
  } else if (bid < PT_T + PT_S) {
    // skip [B, D1C, NPT] -> featB[.][0..127] bf16
    int id = bid - PT_T;
    int z = id >> 10;           // 1024 blocks per batch
    int r = id & 1023;
    int n0 = (r & 255) * 32;    // over NPT
    int d0 = (r >> 8) * 32;     // over D1C
#pragma unroll
    for (int i = 0; i < 32; i += 8)
      tile[ty + i][tx] = skip[((size_t)z * D1C + d0 + ty + i) * NPT + n0 + tx];
    __syncthreads();
#pragma unroll
    for (int i = 0; i < 32; i += 8) {
      int n = n0 + ty + i;
      featB[((size_t)z * NPT + n) * CIN + d0 + tx] = f2bf(tile[tx][ty + i]);
    }
  } else {
    int g = (bid - PT_T - PT_S) * 256 + tid;
    if (g == 0) { ctrs[0] = 0; ctrs[1] = 0; }
    if (g < C1 * CIN) W1h[g] = f2bf(W1[g]);
    if (g < C2 * C1)  W2h[g] = f2bf(W2[g]);
    if (g < BATCH * NSMP) {
      int b = g >> 11, s = g & (NSMP - 1);
      const float* sp = spos + (size_t)b * 3 * NSMP;
      float x = sp[s], y = sp[NSMP + s], z = sp[2 * NSMP + s];
      sposI[(size_t)g * 3 + 0] = x;
      sposI[(size_t)g * 3 + 1] = y;
      sposI[(size_t)g * 3 + 2] = z;
      qs4[g] = make_float4(-2.f * x, -2.f * y, -2.f * z,
                           fmaf(x, x, fmaf(y, y, z * z)));
    }
  }
}

// ---------------------------------------------------------------------------
// knn_all: scan + certification + in-block exact fp64 fallback + interp.
// 256 blocks x 512 thr; each block owns 256 points; each LANE owns 4 points
// (n0+lane, +64, +128, +192). R4 lesson: uniform per-lane VMEM loads are
// TA-bound (~16cyc/wave64 instr regardless of uniformity) -> 55us floor at
// 1 pt/lane. 4 pts/lane amortizes each load over 4 insertion chains:
// TA floor 14us, VALU floor ~17us -> scan is finally VALU-bound.
// R2 lesson: keep +pp (packed key must be the true small distance near 0).
// idx/wgt live only in LDS; interp consumes them in-block (3 kernels fused).
// ---------------------------------------------------------------------------
constexpr int KWAVES = 8;
constexpr int SEGK = NSMP / KWAVES;  // 256 candidates per wave

__device__ __forceinline__ void ins_med3(float kf, float& k0, float& k1,
                                         float& k2, float& k3) {
  float o0 = k0, o1 = k1, o2 = k2;
  k0 = fminf(kf, o0);
  k1 = __builtin_amdgcn_fmed3f(kf, o0, o1);
  k2 = __builtin_amdgcn_fmed3f(kf, o1, o2);
  k3 = __builtin_amdgcn_fmed3f(kf, o2, k3);
}

__device__ __forceinline__ bool dless(double d, int i, double D, int I) {
  return d < D || (d == D && i < I);
}
__device__ __forceinline__ void dins3(double d, int i,
                                      double& b0, double& b1, double& b2,
                                      int& i0, int& i1, int& i2) {
  if (dless(d, i, b2, i2)) {
    if (dless(d, i, b1, i1)) {
      b2 = b1; i2 = i1;
      if (dless(d, i, b0, i0)) { b1 = b0; i1 = i0; b0 = d; i0 = i; }
      else                     { b1 = d; i1 = i; }
    } else { b2 = d; i2 = i; }
  }
}

__global__ __launch_bounds__(512, 4) void knn_all(
    const float* __restrict__ pos,    // [B,3,NPT]
    const float4* __restrict__ qs4g,  // [B,NSMP] transformed
    const float* __restrict__ sposI,  // [B,NSMP,3] original (fp64 paths)
    const float* __restrict__ sfeatT, // [B,NSMP,D2C]
    unsigned short* __restrict__ featB) {
  __shared__ float mk[KWAVES][4][4][64];  // 32 KB: [wave][slot][ptgrp][lane]
  __shared__ int   il[256][3];            // 3 KB  per-point neighbor idx
  __shared__ float wl[256][3];            // 3 KB  per-point weights
  __shared__ int   fl[256];               // 1 KB  flagged-point list
  __shared__ int   fcnt;

  int tid = threadIdx.x;
  int wave = tid >> 6, lane = tid & 63;
  int blk = blockIdx.x;
  int b = blk >> 5;              // 32 blocks per batch
  int n0 = (blk & 31) << 8;      // 256 points per block

  if (tid == 0) fcnt = 0;

  const float* pb = pos + (size_t)b * 3 * NPT;
  float px[4], py[4], pz[4], pp[4];
#pragma unroll
  for (int m = 0; m < 4; m++) {
    int n = n0 + (m << 6) + lane;
    px[m] = pb[n]; py[m] = pb[NPT + n]; pz[m] = pb[2 * NPT + n];
    pp[m] = fmaf(px[m], px[m], fmaf(py[m], py[m], pz[m] * pz[m]));
  }

  const float INF = __builtin_inff();
  float k0[4], k1[4], k2[4], k3[4];
#pragma unroll
  for (int m = 0; m < 4; m++) { k0[m] = INF; k1[m] = INF; k2[m] = INF; k3[m] = INF; }

  int s0 = wave * SEGK;
  int tv = 0;
  asm volatile("" : "+v"(tv));   // opaque zero -> per-lane vector loads
  const float4* qseg = qs4g + (size_t)b * NSMP + s0 + tv;

#define KSTEP4(Q, SS)                                                        \
  {                                                                          \
    _Pragma("unroll")                                                        \
    for (int m_ = 0; m_ < 4; m_++) {                                         \
      float tt = (Q).w + pp[m_];  /* recenter: d small near neighbors */     \
      float d_ = fmaf(px[m_], (Q).x,                                         \
                      fmaf(py[m_], (Q).y, fmaf(pz[m_], (Q).z, tt)));         \
      unsigned ki_ = (__builtin_bit_cast(unsigned, d_) & 0xFFFFF800u) |      \
                     (unsigned)(SS);                                         \
      ins_med3(__builtin_bit_cast(float, ki_), k0[m_], k1[m_], k2[m_], k3[m_]); \
    }                                                                        \
  }

  float4 qa[4], qb[4];
#pragma unroll
  for (int u = 0; u < 4; u++) qa[u] = qseg[u];
#pragma unroll
  for (int u = 0; u < 4; u++) qb[u] = qseg[4 + u];

  for (int t = 0; t < SEGK - 8; t += 8) {
    __builtin_amdgcn_sched_barrier(0);
#pragma unroll
    for (int u = 0; u < 4; u++) KSTEP4(qa[u], s0 + t + u)
    __builtin_amdgcn_sched_barrier(0);
#pragma unroll
    for (int u = 0; u < 4; u++) qa[u] = qseg[t + 8 + u];
    __builtin_amdgcn_sched_barrier(0);
#pragma unroll
    for (int u = 0; u < 4; u++) KSTEP4(qb[u], s0 + t + 4 + u)
    __builtin_amdgcn_sched_barrier(0);
#pragma unroll
    for (int u = 0; u < 4; u++) qb[u] = qseg[t + 12 + u];
  }
  __builtin_amdgcn_sched_barrier(0);
#pragma unroll
  for (int u = 0; u < 4; u++) KSTEP4(qa[u], s0 + SEGK - 8 + u)
#pragma unroll
  for (int u = 0; u < 4; u++) KSTEP4(qb[u], s0 + SEGK - 4 + u)
#undef KSTEP4

#pragma unroll
  for (int m = 0; m < 4; m++) {
    mk[wave][0][m][lane] = k0[m];
    mk[wave][1][m][lane] = k1[m];
    mk[wave][2][m][lane] = k2[m];
    mk[wave][3][m][lane] = k3[m];
  }
  __syncthreads();

  // ---- per-point finalize (256 threads), flag + fp64 weights into LDS ----
  if (tid < 256) {
    int pm = tid >> 6, pl = tid & 63;
    float K0 = INF, K1 = INF, K2 = INF, K3 = INF;
#pragma unroll
    for (int w = 0; w < KWAVES; w++)
#pragma unroll
      for (int sl = 0; sl < 4; sl++)
        ins_med3(mk[w][sl][pm][pl], K0, K1, K2, K3);

    int I0 = (int)(__builtin_bit_cast(unsigned, K0) & 0x7FFu);
    int I1 = (int)(__builtin_bit_cast(unsigned, K1) & 0x7FFu);
    int I2 = (int)(__builtin_bit_cast(unsigned, K2) & 0x7FFu);
    float d2m = __builtin_bit_cast(float, __builtin_bit_cast(unsigned, K2) & 0xFFFFF800u);
    float d3m = __builtin_bit_cast(float, __builtin_bit_cast(unsigned, K3) & 0xFFFFF800u);
    bool flag = (d3m - d2m) < 2e-3f * fmaxf(d3m, 0.f) + 1e-5f;
    if (flag) {
      int slot = atomicAdd(&fcnt, 1);
      fl[slot] = tid;
    }
    int n = n0 + tid;
    const float* q = sposI + (size_t)b * 3 * NSMP;
    double pxd = (double)pb[n], pyd = (double)pb[NPT + n], pzd = (double)pb[2 * NPT + n];
    double dd[3]; int II[3] = {I0, I1, I2};
#pragma unroll
    for (int k = 0; k < 3; k++) {
      double dx = pxd - (double)q[3 * II[k]];
      double dy = pyd - (double)q[3 * II[k] + 1];
      double dz = pzd - (double)q[3 * II[k] + 2];
      dd[k] = dx * dx + dy * dy + dz * dz;
    }
    double w0 = 1.0 / (dd[0] + 1e-8);
    double w1 = 1.0 / (dd[1] + 1e-8);
    double w2 = 1.0 / (dd[2] + 1e-8);
    double inv = 1.0 / (w0 + w1 + w2);
    il[tid][0] = I0; il[tid][1] = I1; il[tid][2] = I2;
    wl[tid][0] = (float)(w0 * inv);
    wl[tid][1] = (float)(w1 * inv);
    wl[tid][2] = (float)(w2 * inv);
  }
  __syncthreads();

  // ---- exact fp64 fallback for flagged points, one wave per point ----
  int fc = fcnt;
  for (int t = wave; t < fc; t += KWAVES) {
    int P = fl[t];
    int n = n0 + P;
    double pxd = (double)pb[n], pyd = (double)pb[NPT + n], pzd = (double)pb[2 * NPT + n];
    const float* q = sposI + (size_t)b * 3 * NSMP;
    double b0 = 1e300, b1 = 1e300, b2 = 1e300;
    int i0 = 0x7FFFFFFF, i1 = 0x7FFFFFFF, i2 = 0x7FFFFFFF;
    for (int s = lane; s < NSMP; s += 64) {
      double dx = pxd - (double)q[3 * s];
      double dy = pyd - (double)q[3 * s + 1];
      double dz = pzd - (double)q[3 * s + 2];
      double d = dx * dx + dy * dy + dz * dz;
      dins3(d, s, b0, b1, b2, i0, i1, i2);
    }
#pragma unroll
    for (int m = 1; m < 64; m <<= 1) {
      double o0 = __shfl_xor(b0, m, 64), o1 = __shfl_xor(b1, m, 64), o2 = __shfl_xor(b2, m, 64);
      int    j0 = __shfl_xor(i0, m, 64), j1 = __shfl_xor(i1, m, 64), j2 = __shfl_xor(i2, m, 64);
      dins3(o0, j0, b0, b1, b2, i0, i1, i2);
      dins3(o1, j1, b0, b1, b2, i0, i1, i2);
      dins3(o2, j2, b0, b1, b2, i0, i1, i2);
    }
    if (lane == 0) {
      double w0 = 1.0 / (b0 + 1e-8);
      double w1 = 1.0 / (b1 + 1e-8);
      double w2 = 1.0 / (b2 + 1e-8);
      double inv = 1.0 / (w0 + w1 + w2);
      il[P][0] = i0; il[P][1] = i1; il[P][2] = i2;
      wl[P][0] = (float)(w0 * inv);
      wl[P][1] = (float)(w1 * inv);
      wl[P][2] = (float)(w2 * inv);
    }
  }
  __syncthreads();

  // ---- interp: each wave handles 32 points; lane covers 4 channels ----
  const float* base = sfeatT + (size_t)b * NSMP * D2C;
  for (int i = 0; i < 32; i++) {
    int P = (wave << 5) + i;
    int i0 = il[P][0], i1 = il[P][1], i2 = il[P][2];
    float w0 = wl[P][0], w1 = wl[P][1], w2 = wl[P][2];
    float4 v0 = *(const float4*)&base[(size_t)i0 * D2C + (lane << 2)];
    float4 v1 = *(const float4*)&base[(size_t)i1 * D2C + (lane << 2)];
    float4 v2 = *(const float4*)&base[(size_t)i2 * D2C + (lane << 2)];
    u16x4 o;
    o[0] = f2bf(w0 * v0.x + w1 * v1.x + w2 * v2.x);
    o[1] = f2bf(w0 * v0.y + w1 * v1.y + w2 * v2.y);
    o[2] = f2bf(w0 * v0.z + w1 * v1.z + w2 * v2.z);
    o[3] = f2bf(w0 * v0.w + w1 * v1.w + w2 * v2.w);
    *(u16x4*)&featB[((size_t)b * NPT + n0 + P) * CIN + D1C + (lane << 2)] = o;
  }
}

// ---------------------------------------------------------------------------
// GEMM1, 4-wave 128x128 tile (m97 structure): Y1 = featB @ W1^T + b1.
// Last finishing block reduces BN1 partials -> scale1/shift1 (saves a node).
// ---------------------------------------------------------------------------
__global__ __launch_bounds__(256) void gemm1_mw(
    const unsigned short* __restrict__ featB,  // [BN_TOTAL][CIN] bf16
    const unsigned short* __restrict__ W1h,    // [C1][CIN] bf16
    const float* __restrict__ bias,
    unsigned short* __restrict__ Y1,           // [BN_TOTAL][C1] bf16
    float* __restrict__ part_s,                // [C1][NRW]
    float* __restrict__ part_q,
    const float* __restrict__ g1, const float* __restrict__ beta1,
    float* __restrict__ scale1, float* __restrict__ shift1,
    int* __restrict__ ctr) {
  __shared__ __align__(16) unsigned short As[BM * BK];  // 8 KB
  __shared__ __align__(16) unsigned short Bs[BM * BK];  // 8 KB
  int tid = threadIdx.x;
  int lane = tid & 63, w = tid >> 6;
  int wr = w >> 1, wc = w & 1;
  int m16 = lane & 15, quad = lane >> 4;
  int cb = blockIdx.x, rb = blockIdx.y;
  int row0 = rb * BM, col0 = cb * BM;
  int srow = lane >> 2, scol8 = (lane & 3) * 8;

  f32x4 acc[4][4];
#pragma unroll
  for (int j = 0; j < 4; j++) {
    float bj = bias[col0 + wc * 64 + j * 16 + m16];
#pragma unroll
    for (int i = 0; i < 4; i++) acc[i][j] = f32x4{bj, bj, bj, bj};
  }

  for (int k0 = 0; k0 < CIN; k0 += BK) {
#pragma unroll
    for (int kq = 0; kq < 2; kq++) {
      int ar = 32 * w + 16 * kq + srow;
      int lb = __builtin_amdgcn_readfirstlane((32 * w + 16 * kq) * BK);
      gld_lds16(&featB[(size_t)(row0 + ar) * CIN + k0 + scol8], &As[lb]);
      gld_lds16(&W1h[(size_t)(col0 + ar) * CIN + k0 + scol8], &Bs[lb]);
    }
    __syncthreads();

    bf16x8 a[4], bb[4];
#pragma unroll
    for (int i = 0; i < 4; i++)
      a[i] = __builtin_bit_cast(bf16x8,
          *(const s16x8*)&As[(wr * 64 + i * 16 + m16) * BK + quad * 8]);
#pragma unroll
    for (int j = 0; j < 4; j++)
      bb[j] = __builtin_bit_cast(bf16x8,
          *(const s16x8*)&Bs[(wc * 64 + j * 16 + m16) * BK + quad * 8]);
#pragma unroll
    for (int i = 0; i < 4; i++)
#pragma unroll
      for (int j = 0; j < 4; j++)
        acc[i][j] = __builtin_amdgcn_mfma_f32_16x16x32_bf16(a[i], bb[j], acc[i][j], 0, 0, 0);
    __syncthreads();
  }

#pragma unroll
  for (int j = 0; j < 4; j++) {
    int col = col0 + wc * 64 + j * 16 + m16;
    float s = 0.f, q = 0.f;
#pragma unroll
    for (int i = 0; i < 4; i++)
#pragma unroll
      for (int r = 0; r < 4; r++) {
        float v = acc[i][j][r];
        Y1[(size_t)(row0 + wr * 64 + i * 16 + quad * 4 + r) * C1 + col] = f2bf(v);
        s += v; q = fmaf(v, v, q);
      }
    s += __shfl_xor(s, 16, 64); s += __shfl_xor(s, 32, 64);
    q += __shfl_xor(q, 16, 64); q += __shfl_xor(q, 32, 64);
    if (quad == 0) {
      part_s[(size_t)col * NRW + rb * 2 + wr] = s;
      part_q[(size_t)col * NRW + rb * 2 + wr] = q;
    }
  }

  // last-block BN1 reduction (threadfence pattern)
  __threadfence();
  __shared__ int isLast;
  if (tid == 0)
    isLast = (atomicAdd(ctr, 1) == (int)(gridDim.x * gridDim.y) - 1);
  __syncthreads();
  if (isLast) {
    __threadfence();
    int ch = tid;  // 256 threads == C1 channels
    const float4* ps = (const float4*)&part_s[(size_t)ch * NRW];
    const float4* pq = (const float4*)&part_q[(size_t)ch * NRW];
    float s = 0.f, q = 0.f;
    for (int t = 0; t < NRW / 4; t++) {
      float4 a = ps[t], c = pq[t];
      s += a.x + a.y + a.z + a.w;
      q += c.x + c.y + c.z + c.w;
    }
    const float invBN = 1.0f / (float)BN_TOTAL;
    float mean = s * invBN;
    float var = q * invBN - mean * mean;
    float sc = g1[ch] / sqrtf(var + 1e-5f);
    scale1[ch] = sc;
    shift1[ch] = beta1[ch] - mean * sc;
  }
}

// ---------------------------------------------------------------------------
// GEMM2, 4-wave 128x128 tile: X2 = relu(bn1(Y1)) fused in reg-staged A,
// B via global_load_lds. grid = NRB. Last block reduces BN2 partials.
// ---------------------------------------------------------------------------
__global__ __launch_bounds__(256) void gemm2_mw(
    const unsigned short* __restrict__ Y1,   // [BN_TOTAL][C1] bf16
    const float* __restrict__ scale1, const float* __restrict__ shift1,
    const unsigned short* __restrict__ W2h,  // [C2][C1] bf16
    const float* __restrict__ bias,
    unsigned short* __restrict__ Y2,         // [BN_TOTAL][C2] bf16
    float* __restrict__ part_s,              // [C2][NRW]
    float* __restrict__ part_q,
    const float* __restrict__ g2, const float* __restrict__ beta2,
    float* __restrict__ scale2, float* __restrict__ shift2,
    int* __restrict__ ctr) {
  __shared__ __align__(16) unsigned short As[BM * BK];
  __shared__ __align__(16) unsigned short Bs[BM * BK];
  __shared__ float scs[C1], shs[C1];
  int tid = threadIdx.x;
  int lane = tid & 63, w = tid >> 6;
  int wr = w >> 1, wc = w & 1;
  int m16 = lane & 15, quad = lane >> 4;
  int rb = blockIdx.x;
  int row0 = rb * BM, col0 = 0;
  int srow = lane >> 2, scol8 = (lane & 3) * 8;

  scs[tid] = scale1[tid]; shs[tid] = shift1[tid];  // C1 == blockDim

  f32x4 acc[4][4];
#pragma unroll
  for (int j = 0; j < 4; j++) {
    float bj = bias[col0 + wc * 64 + j * 16 + m16];
#pragma unroll
    for (int i = 0; i < 4; i++) acc[i][j] = f32x4{bj, bj, bj, bj};
  }
  __syncthreads();

  for (int k0 = 0; k0 < C1; k0 += BK) {
#pragma unroll
    for (int kq = 0; kq < 2; kq++) {
      int ar = 32 * w + 16 * kq + srow;
      int lb = __builtin_amdgcn_readfirstlane((32 * w + 16 * kq) * BK);
      gld_lds16(&W2h[(size_t)(col0 + ar) * C1 + k0 + scol8], &Bs[lb]);
      // A tile: load Y1, apply BN1+ReLU, write LDS
      s16x8 v = *(const s16x8*)&Y1[(size_t)(row0 + ar) * C1 + k0 + scol8];
      unsigned short ov[8];
#pragma unroll
      for (int e = 0; e < 8; e++) {
        float x = bf2f((unsigned short)v[e]);
        float y = fmaxf(fmaf(x, scs[k0 + scol8 + e], shs[k0 + scol8 + e]), 0.f);
        ov[e] = f2bf(y);
      }
      *(s16x8*)&As[ar * BK + scol8] = *(const s16x8*)ov;
    }
    __syncthreads();

    bf16x8 a[4], bb[4];
#pragma unroll
    for (int i = 0; i < 4; i++)
      a[i] = __builtin_bit_cast(bf16x8,
          *(const s16x8*)&As[(wr * 64 + i * 16 + m16) * BK + quad * 8]);
#pragma unroll
    for (int j = 0; j < 4; j++)
      bb[j] = __builtin_bit_cast(bf16x8,
          *(const s16x8*)&Bs[(wc * 64 + j * 16 + m16) * BK + quad * 8]);
#pragma unroll
    for (int i = 0; i < 4; i++)
#pragma unroll
      for (int j = 0; j < 4; j++)
        acc[i][j] = __builtin_amdgcn_mfma_f32_16x16x32_bf16(a[i], bb[j], acc[i][j], 0, 0, 0);
    __syncthreads();
  }

#pragma unroll
  for (int j = 0; j < 4; j++) {
    int col = col0 + wc * 64 + j * 16 + m16;
    float s = 0.f, q = 0.f;
#pragma unroll
    for (int i = 0; i < 4; i++)
#pragma unroll
      for (int r = 0; r < 4; r++) {
        float v = acc[i][j][r];
        Y2[(size_t)(row0 + wr * 64 + i * 16 + quad * 4 + r) * C2 + col] = f2bf(v);
        s += v; q = fmaf(v, v, q);
      }
    s += __shfl_xor(s, 16, 64); s += __shfl_xor(s, 32, 64);
    q += __shfl_xor(q, 16, 64); q += __shfl_xor(q, 32, 64);
    if (quad == 0) {
      part_s[(size_t)col * NRW + rb * 2 + wr] = s;
      part_q[(size_t)col * NRW + rb * 2 + wr] = q;
    }
  }

  // last-block BN2 reduction
  __threadfence();
  __shared__ int isLast;
  if (tid == 0) isLast = (atomicAdd(ctr, 1) == (int)gridDim.x - 1);
  __syncthreads();
  if (isLast && tid < C2) {
    __threadfence();
    int ch = tid;
    const float4* ps = (const float4*)&part_s[(size_t)ch * NRW];
    const float4* pq = (const float4*)&part_q[(size_t)ch * NRW];
    float s = 0.f, q = 0.f;
    for (int t = 0; t < NRW / 4; t++) {
      float4 a = ps[t], c = pq[t];
      s += a.x + a.y + a.z + a.w;
      q += c.x + c.y + c.z + c.w;
    }
    const float invBN = 1.0f / (float)BN_TOTAL;
    float mean = s * invBN;
    float var = q * invBN - mean * mean;
    float sc = g2[ch] / sqrtf(var + 1e-5f);
    scale2[ch] = sc;
    shift2[ch] = beta2[ch] - mean * sc;
  }
}

// ---------------------------------------------------------------------------
// Final: out[b][c][n] = relu(bn2(Y2)) transposed, fp32 out.
// ---------------------------------------------------------------------------
__global__ void final_kernel(const unsigned short* __restrict__ Y2,
                             const float* __restrict__ scale, const float* __restrict__ shift,
                             float* __restrict__ out) {
  __shared__ float tile[32][33];
  int b = blockIdx.z;
  int n0 = blockIdx.x * 32;
  int c0 = blockIdx.y * 32;
  int tx = threadIdx.x, ty = threadIdx.y;
  float sc = scale[c0 + tx];
  float sh = shift[c0 + tx];
#pragma unroll
  for (int i = 0; i < 32; i += 8) {
    int n = n0 + ty + i;
    float v = bf2f(Y2[((size_t)b * NPT + n) * C2 + c0 + tx]);
    tile[ty + i][tx] = fmaxf(fmaf(v, sc, sh), 0.f);
  }
  __syncthreads();
#pragma unroll
  for (int i = 0; i < 32; i += 8) {
    int c = c0 + ty + i;
    out[((size_t)b * C2 + c) * NPT + n0 + tx] = tile[tx][ty + i];
  }
}

// ---------------------------------------------------------------------------
extern "C" void kernel_launch(void* const* d_in, const int* in_sizes, int n_in,
                              void* d_out, int out_size, void* d_ws, size_t ws_size,
                              hipStream_t stream) {
  (void)in_sizes; (void)n_in; (void)out_size; (void)ws_size;
  const float* pos   = (const float*)d_in[0];
  const float* spos  = (const float*)d_in[1];
  const float* skip  = (const float*)d_in[2];
  const float* sfeat = (const float*)d_in[3];
  const float* W1    = (const float*)d_in[4];
  const float* b1    = (const float*)d_in[5];
  const float* g1    = (const float*)d_in[6];
  const float* beta1 = (const float*)d_in[7];
  const float* W2    = (const float*)d_in[8];
  const float* b2    = (const float*)d_in[9];
  const float* g2    = (const float*)d_in[10];
  const float* beta2 = (const float*)d_in[11];
  float* out = (float*)d_out;

  float* ws = (float*)d_ws;
  size_t off = 0;
  float* sfeatT  = ws + off; off += (size_t)BATCH * NSMP * D2C;
  unsigned short* featB = (unsigned short*)(ws + off); off += (size_t)BN_TOTAL * CIN / 2;
  unsigned short* Y1    = (unsigned short*)(ws + off); off += (size_t)BN_TOTAL * C1 / 2;
  unsigned short* Y2    = (unsigned short*)(ws + off); off += (size_t)BN_TOTAL * C2 / 2;
  unsigned short* W1h   = (unsigned short*)(ws + off); off += (size_t)C1 * CIN / 2;
  unsigned short* W2h   = (unsigned short*)(ws + off); off += (size_t)C2 * C1 / 2;
  float* sposI   = ws + off; off += (size_t)BATCH * NSMP * 3;
  float4* qs4    = (float4*)(ws + off); off += (size_t)BATCH * NSMP * 4;
  float* part1_s = ws + off; off += (size_t)C1 * NRW;
  float* part1_q = ws + off; off += (size_t)C1 * NRW;
  float* part2_s = ws + off; off += (size_t)C2 * NRW;
  float* part2_q = ws + off; off += (size_t)C2 * NRW;
  float* stats   = ws + off; off += 2048;
  int*   ctrs    = (int*)stats;            // [0]=gemm1 ctr, [1]=gemm2 ctr
  float* scale1 = stats + 256, *shift1 = stats + 512;
  float* scale2 = stats + 768, *shift2 = stats + 1024;

  prep_all<<<PT_T + PT_S + PT_M, 256, 0, stream>>>(
      sfeat, sfeatT, skip, featB, spos, sposI, qs4, W1, W1h, W2, W2h, ctrs);

  knn_all<<<BN_TOTAL / 256, 512, 0, stream>>>(pos, qs4, sposI, sfeatT, featB);

  gemm1_mw<<<dim3(C1 / BM, NRB), 256, 0, stream>>>(
      featB, W1h, b1, Y1, part1_s, part1_q, g1, beta1, scale1, shift1, &ctrs[0]);

  gemm2_mw<<<NRB, 256, 0, stream>>>(
      Y1, scale1, shift1, W2h, b2, Y2, part2_s, part2_q,
      g2, beta2, scale2, shift2, &ctrs[1]);

  final_kernel<<<dim3(NPT / 32, C2 / 32, BATCH), dim3(32, 8), 0, stream>>>(
      Y2, scale2, shift2, out);
}

// Round 6
// 291.576 us; speedup vs baseline: 2.0631x; 2.0631x over previous
//
#include <hip/hip_runtime.h>

// Problem constants
constexpr int BATCH = 8;
constexpr int NPT   = 8192;   // N points
constexpr int NSMP  = 2048;   // S sampled points
constexpr int D1C   = 128;    // skip feature channels
constexpr int D2C   = 256;    // sampled feature channels
constexpr int CIN   = 384;    // D1C + D2C
constexpr int C1    = 256;    // layer-1 out channels
constexpr int C2    = 128;    // layer-2 out channels
constexpr int BN_TOTAL = BATCH * NPT;  // 65536 rows

// Multi-wave GEMM tiling: 4 waves (256 thr), 128x128 tile, BK=32 (m97 structure)
constexpr int BM = 128, BK = 32;
constexpr int NRB = BN_TOTAL / BM;   // 512 row-blocks

typedef __bf16 bf16x8 __attribute__((ext_vector_type(8)));
typedef short  s16x8  __attribute__((ext_vector_type(8)));
typedef float  f32x4  __attribute__((ext_vector_type(4)));
typedef unsigned short u16x4 __attribute__((ext_vector_type(4)));

__device__ __forceinline__ unsigned short f2bf(float x) {
  unsigned u = __builtin_bit_cast(unsigned, x);
  u += 0x7fffu + ((u >> 16) & 1u);   // round-to-nearest-even
  return (unsigned short)(u >> 16);
}
__device__ __forceinline__ float bf2f(unsigned short h) {
  return __builtin_bit_cast(float, (unsigned)h << 16);
}

// async global -> LDS, 16 B per lane; lds dest wave-uniform base + lane*16
__device__ __forceinline__ void gld_lds16(const void* g, void* l) {
  __builtin_amdgcn_global_load_lds(
      (const __attribute__((address_space(1))) void*)g,
      (__attribute__((address_space(3))) void*)l, 16, 0, 0);
}

// ---------------------------------------------------------------------------
// prep_all: fused transpose(sfeat->sfeatT) + skip->featB + W casts + spos pack
// + BN-stat zeroing. Role selected by block-index range. 5 graph nodes total.
// R5 lesson: NO __threadfence-based cross-block reductions on CDNA4 —
// device fences writeback/invalidate per-XCD L2 (gemm1 went 50->235us).
// BN stats flow through device-scope float atomics instead (coherent point,
// no fence needed; guide G12).
// ---------------------------------------------------------------------------
constexpr int PT_T = (NSMP / 32) * (D2C / 32) * BATCH;  // 4096 transpose blocks
constexpr int PT_S = (NPT / 32) * (D1C / 32) * BATCH;   // 8192 skip blocks
constexpr int PT_M = (C1 * CIN + 255) / 256;            // 384 misc blocks

__global__ __launch_bounds__(256) void prep_all(
    const float* __restrict__ sfeat, float* __restrict__ sfeatT,
    const float* __restrict__ skip, unsigned short* __restrict__ featB,
    const float* __restrict__ spos, float* __restrict__ sposI,
    float4* __restrict__ qs4,
    const float* __restrict__ W1, unsigned short* __restrict__ W1h,
    const float* __restrict__ W2, unsigned short* __restrict__ W2h,
    float* __restrict__ stats) {   // [0..255]=sum1 [256..511]=sumsq1
                                   // [512..639]=sum2 [640..767]=sumsq2
  __shared__ float tile[32][33];
  int bid = blockIdx.x, tid = threadIdx.x;
  int tx = tid & 31, ty = tid >> 5;
  if (bid < PT_T) {
    // transpose sfeat [B, D2C, NSMP] -> sfeatT [B, NSMP, D2C]
    int z = bid >> 9;           // 512 blocks per batch
    int r = bid & 511;
    int c0 = (r & 63) * 32;     // over NSMP
    int r0 = (r >> 6) * 32;     // over D2C
    const float* inb = sfeat + (size_t)z * D2C * NSMP;
    float* outb = sfeatT + (size_t)z * NSMP * D2C;
#pragma unroll
    for (int i = 0; i < 32; i += 8)
      tile[ty + i][tx] = inb[(size_t)(r0 + ty + i) * NSMP + c0 + tx];
    __syncthreads();
#pragma unroll
    for (int i = 0; i < 32; i += 8)
      outb[(size_t)(c0 + ty + i) * D2C + r0 + tx] = tile[tx][ty + i];
  } else if (bid < PT_T + PT_S) {
    // skip [B, D1C, NPT] -> featB[.][0..127] bf16
    int id = bid - PT_T;
    int z = id >> 10;           // 1024 blocks per batch
    int r = id & 1023;
    int n0 = (r & 255) * 32;    // over NPT
    int d0 = (r >> 8) * 32;     // over D1C
#pragma unroll
    for (int i = 0; i < 32; i += 8)
      tile[ty + i][tx] = skip[((size_t)z * D1C + d0 + ty + i) * NPT + n0 + tx];
    __syncthreads();
#pragma unroll
    for (int i = 0; i < 32; i += 8) {
      int n = n0 + ty + i;
      featB[((size_t)z * NPT + n) * CIN + d0 + tx] = f2bf(tile[tx][ty + i]);
    }
  } else {
    int g = (bid - PT_T - PT_S) * 256 + tid;
    if (g < 768) stats[g] = 0.f;
    if (g < C1 * CIN) W1h[g] = f2bf(W1[g]);
    if (g < C2 * C1)  W2h[g] = f2bf(W2[g]);
    if (g < BATCH * NSMP) {
      int b = g >> 11, s = g & (NSMP - 1);
      const float* sp = spos + (size_t)b * 3 * NSMP;
      float x = sp[s], y = sp[NSMP + s], z = sp[2 * NSMP + s];
      sposI[(size_t)g * 3 + 0] = x;
      sposI[(size_t)g * 3 + 1] = y;
      sposI[(size_t)g * 3 + 2] = z;
      qs4[g] = make_float4(-2.f * x, -2.f * y, -2.f * z,
                           fmaf(x, x, fmaf(y, y, z * z)));
    }
  }
}

// ---------------------------------------------------------------------------
// knn_all: scan + certification + in-block exact fp64 fallback + interp.
// 256 blocks x 512 thr; each block owns 256 points; each LANE owns 4 points.
// R4 lesson: uniform per-lane VMEM loads are TA-bound (~16cyc/wave64 instr)
// -> 4 pts/lane amortizes each load over 4 insertion chains (TA 14us, VALU
// ~17us floors). R2 lesson: keep +pp (packed key = true small distance).
// idx/wgt live only in LDS; interp consumes them in-block.
// ---------------------------------------------------------------------------
constexpr int KWAVES = 8;
constexpr int SEGK = NSMP / KWAVES;  // 256 candidates per wave

__device__ __forceinline__ void ins_med3(float kf, float& k0, float& k1,
                                         float& k2, float& k3) {
  float o0 = k0, o1 = k1, o2 = k2;
  k0 = fminf(kf, o0);
  k1 = __builtin_amdgcn_fmed3f(kf, o0, o1);
  k2 = __builtin_amdgcn_fmed3f(kf, o1, o2);
  k3 = __builtin_amdgcn_fmed3f(kf, o2, k3);
}

__device__ __forceinline__ bool dless(double d, int i, double D, int I) {
  return d < D || (d == D && i < I);
}
__device__ __forceinline__ void dins3(double d, int i,
                                      double& b0, double& b1, double& b2,
                                      int& i0, int& i1, int& i2) {
  if (dless(d, i, b2, i2)) {
    if (dless(d, i, b1, i1)) {
      b2 = b1; i2 = i1;
      if (dless(d, i, b0, i0)) { b1 = b0; i1 = i0; b0 = d; i0 = i; }
      else                     { b1 = d; i1 = i; }
    } else { b2 = d; i2 = i; }
  }
}

__global__ __launch_bounds__(512, 4) void knn_all(
    const float* __restrict__ pos,    // [B,3,NPT]
    const float4* __restrict__ qs4g,  // [B,NSMP] transformed
    const float* __restrict__ sposI,  // [B,NSMP,3] original (fp64 paths)
    const float* __restrict__ sfeatT, // [B,NSMP,D2C]
    unsigned short* __restrict__ featB) {
  __shared__ float mk[KWAVES][4][4][64];  // 32 KB: [wave][slot][ptgrp][lane]
  __shared__ int   il[256][3];            // 3 KB  per-point neighbor idx
  __shared__ float wl[256][3];            // 3 KB  per-point weights
  __shared__ int   fl[256];               // 1 KB  flagged-point list
  __shared__ int   fcnt;

  int tid = threadIdx.x;
  int wave = tid >> 6, lane = tid & 63;
  int blk = blockIdx.x;
  int b = blk >> 5;              // 32 blocks per batch
  int n0 = (blk & 31) << 8;      // 256 points per block

  if (tid == 0) fcnt = 0;

  const float* pb = pos + (size_t)b * 3 * NPT;
  float px[4], py[4], pz[4], pp[4];
#pragma unroll
  for (int m = 0; m < 4; m++) {
    int n = n0 + (m << 6) + lane;
    px[m] = pb[n]; py[m] = pb[NPT + n]; pz[m] = pb[2 * NPT + n];
    pp[m] = fmaf(px[m], px[m], fmaf(py[m], py[m], pz[m] * pz[m]));
  }

  const float INF = __builtin_inff();
  float k0[4], k1[4], k2[4], k3[4];
#pragma unroll
  for (int m = 0; m < 4; m++) { k0[m] = INF; k1[m] = INF; k2[m] = INF; k3[m] = INF; }

  int s0 = wave * SEGK;
  int tv = 0;
  asm volatile("" : "+v"(tv));   // opaque zero -> per-lane vector loads
  const float4* qseg = qs4g + (size_t)b * NSMP + s0 + tv;

#define KSTEP4(Q, SS)                                                        \
  {                                                                          \
    _Pragma("unroll")                                                        \
    for (int m_ = 0; m_ < 4; m_++) {                                         \
      float tt = (Q).w + pp[m_];  /* recenter: d small near neighbors */     \
      float d_ = fmaf(px[m_], (Q).x,                                         \
                      fmaf(py[m_], (Q).y, fmaf(pz[m_], (Q).z, tt)));         \
      unsigned ki_ = (__builtin_bit_cast(unsigned, d_) & 0xFFFFF800u) |      \
                     (unsigned)(SS);                                         \
      ins_med3(__builtin_bit_cast(float, ki_), k0[m_], k1[m_], k2[m_], k3[m_]); \
    }                                                                        \
  }

  float4 qa[4], qb[4];
#pragma unroll
  for (int u = 0; u < 4; u++) qa[u] = qseg[u];
#pragma unroll
  for (int u = 0; u < 4; u++) qb[u] = qseg[4 + u];

  for (int t = 0; t < SEGK - 8; t += 8) {
    __builtin_amdgcn_sched_barrier(0);
#pragma unroll
    for (int u = 0; u < 4; u++) KSTEP4(qa[u], s0 + t + u)
    __builtin_amdgcn_sched_barrier(0);
#pragma unroll
    for (int u = 0; u < 4; u++) qa[u] = qseg[t + 8 + u];
    __builtin_amdgcn_sched_barrier(0);
#pragma unroll
    for (int u = 0; u < 4; u++) KSTEP4(qb[u], s0 + t + 4 + u)
    __builtin_amdgcn_sched_barrier(0);
#pragma unroll
    for (int u = 0; u < 4; u++) qb[u] = qseg[t + 12 + u];
  }
  __builtin_amdgcn_sched_barrier(0);
#pragma unroll
  for (int u = 0; u < 4; u++) KSTEP4(qa[u], s0 + SEGK - 8 + u)
#pragma unroll
  for (int u = 0; u < 4; u++) KSTEP4(qb[u], s0 + SEGK - 4 + u)
#undef KSTEP4

#pragma unroll
  for (int m = 0; m < 4; m++) {
    mk[wave][0][m][lane] = k0[m];
    mk[wave][1][m][lane] = k1[m];
    mk[wave][2][m][lane] = k2[m];
    mk[wave][3][m][lane] = k3[m];
  }
  __syncthreads();

  // ---- per-point finalize (256 threads), flag + fp64 weights into LDS ----
  if (tid < 256) {
    int pm = tid >> 6, pl = tid & 63;
    float K0 = INF, K1 = INF, K2 = INF, K3 = INF;
#pragma unroll
    for (int w = 0; w < KWAVES; w++)
#pragma unroll
      for (int sl = 0; sl < 4; sl++)
        ins_med3(mk[w][sl][pm][pl], K0, K1, K2, K3);

    int I0 = (int)(__builtin_bit_cast(unsigned, K0) & 0x7FFu);
    int I1 = (int)(__builtin_bit_cast(unsigned, K1) & 0x7FFu);
    int I2 = (int)(__builtin_bit_cast(unsigned, K2) & 0x7FFu);
    float d2m = __builtin_bit_cast(float, __builtin_bit_cast(unsigned, K2) & 0xFFFFF800u);
    float d3m = __builtin_bit_cast(float, __builtin_bit_cast(unsigned, K3) & 0xFFFFF800u);
    bool flag = (d3m - d2m) < 2e-3f * fmaxf(d3m, 0.f) + 1e-5f;
    if (flag) {
      int slot = atomicAdd(&fcnt, 1);
      fl[slot] = tid;
    }
    int n = n0 + tid;
    const float* q = sposI + (size_t)b * 3 * NSMP;
    double pxd = (double)pb[n], pyd = (double)pb[NPT + n], pzd = (double)pb[2 * NPT + n];
    double dd[3]; int II[3] = {I0, I1, I2};
#pragma unroll
    for (int k = 0; k < 3; k++) {
      double dx = pxd - (double)q[3 * II[k]];
      double dy = pyd - (double)q[3 * II[k] + 1];
      double dz = pzd - (double)q[3 * II[k] + 2];
      dd[k] = dx * dx + dy * dy + dz * dz;
    }
    double w0 = 1.0 / (dd[0] + 1e-8);
    double w1 = 1.0 / (dd[1] + 1e-8);
    double w2 = 1.0 / (dd[2] + 1e-8);
    double inv = 1.0 / (w0 + w1 + w2);
    il[tid][0] = I0; il[tid][1] = I1; il[tid][2] = I2;
    wl[tid][0] = (float)(w0 * inv);
    wl[tid][1] = (float)(w1 * inv);
    wl[tid][2] = (float)(w2 * inv);
  }
  __syncthreads();

  // ---- exact fp64 fallback for flagged points, one wave per point ----
  int fc = fcnt;
  for (int t = wave; t < fc; t += KWAVES) {
    int P = fl[t];
    int n = n0 + P;
    double pxd = (double)pb[n], pyd = (double)pb[NPT + n], pzd = (double)pb[2 * NPT + n];
    const float* q = sposI + (size_t)b * 3 * NSMP;
    double b0 = 1e300, b1 = 1e300, b2 = 1e300;
    int i0 = 0x7FFFFFFF, i1 = 0x7FFFFFFF, i2 = 0x7FFFFFFF;
    for (int s = lane; s < NSMP; s += 64) {
      double dx = pxd - (double)q[3 * s];
      double dy = pyd - (double)q[3 * s + 1];
      double dz = pzd - (double)q[3 * s + 2];
      double d = dx * dx + dy * dy + dz * dz;
      dins3(d, s, b0, b1, b2, i0, i1, i2);
    }
#pragma unroll
    for (int m = 1; m < 64; m <<= 1) {
      double o0 = __shfl_xor(b0, m, 64), o1 = __shfl_xor(b1, m, 64), o2 = __shfl_xor(b2, m, 64);
      int    j0 = __shfl_xor(i0, m, 64), j1 = __shfl_xor(i1, m, 64), j2 = __shfl_xor(i2, m, 64);
      dins3(o0, j0, b0, b1, b2, i0, i1, i2);
      dins3(o1, j1, b0, b1, b2, i0, i1, i2);
      dins3(o2, j2, b0, b1, b2, i0, i1, i2);
    }
    if (lane == 0) {
      double w0 = 1.0 / (b0 + 1e-8);
      double w1 = 1.0 / (b1 + 1e-8);
      double w2 = 1.0 / (b2 + 1e-8);
      double inv = 1.0 / (w0 + w1 + w2);
      il[P][0] = i0; il[P][1] = i1; il[P][2] = i2;
      wl[P][0] = (float)(w0 * inv);
      wl[P][1] = (float)(w1 * inv);
      wl[P][2] = (float)(w2 * inv);
    }
  }
  __syncthreads();

  // ---- interp: each wave handles 32 points; lane covers 4 channels ----
  const float* base = sfeatT + (size_t)b * NSMP * D2C;
  for (int i = 0; i < 32; i++) {
    int P = (wave << 5) + i;
    int i0 = il[P][0], i1 = il[P][1], i2 = il[P][2];
    float w0 = wl[P][0], w1 = wl[P][1], w2 = wl[P][2];
    float4 v0 = *(const float4*)&base[(size_t)i0 * D2C + (lane << 2)];
    float4 v1 = *(const float4*)&base[(size_t)i1 * D2C + (lane << 2)];
    float4 v2 = *(const float4*)&base[(size_t)i2 * D2C + (lane << 2)];
    u16x4 o;
    o[0] = f2bf(w0 * v0.x + w1 * v1.x + w2 * v2.x);
    o[1] = f2bf(w0 * v0.y + w1 * v1.y + w2 * v2.y);
    o[2] = f2bf(w0 * v0.z + w1 * v1.z + w2 * v2.z);
    o[3] = f2bf(w0 * v0.w + w1 * v1.w + w2 * v2.w);
    *(u16x4*)&featB[((size_t)b * NPT + n0 + P) * CIN + D1C + (lane << 2)] = o;
  }
}

// ---------------------------------------------------------------------------
// GEMM1, 4-wave 128x128 tile (m97 structure): Y1 = featB @ W1^T + b1.
// BN1 stats via device-scope float atomics (no fence, no extra node).
// ---------------------------------------------------------------------------
__global__ __launch_bounds__(256) void gemm1_mw(
    const unsigned short* __restrict__ featB,  // [BN_TOTAL][CIN] bf16
    const unsigned short* __restrict__ W1h,    // [C1][CIN] bf16
    const float* __restrict__ bias,
    unsigned short* __restrict__ Y1,           // [BN_TOTAL][C1] bf16
    float* __restrict__ sum1,                  // [C1]
    float* __restrict__ sumsq1) {              // [C1]
  __shared__ __align__(16) unsigned short As[BM * BK];  // 8 KB
  __shared__ __align__(16) unsigned short Bs[BM * BK];  // 8 KB
  int tid = threadIdx.x;
  int lane = tid & 63, w = tid >> 6;
  int wr = w >> 1, wc = w & 1;
  int m16 = lane & 15, quad = lane >> 4;
  int cb = blockIdx.x, rb = blockIdx.y;
  int row0 = rb * BM, col0 = cb * BM;
  int srow = lane >> 2, scol8 = (lane & 3) * 8;

  f32x4 acc[4][4];
#pragma unroll
  for (int j = 0; j < 4; j++) {
    float bj = bias[col0 + wc * 64 + j * 16 + m16];
#pragma unroll
    for (int i = 0; i < 4; i++) acc[i][j] = f32x4{bj, bj, bj, bj};
  }

  for (int k0 = 0; k0 < CIN; k0 += BK) {
#pragma unroll
    for (int kq = 0; kq < 2; kq++) {
      int ar = 32 * w + 16 * kq + srow;
      int lb = __builtin_amdgcn_readfirstlane((32 * w + 16 * kq) * BK);
      gld_lds16(&featB[(size_t)(row0 + ar) * CIN + k0 + scol8], &As[lb]);
      gld_lds16(&W1h[(size_t)(col0 + ar) * CIN + k0 + scol8], &Bs[lb]);
    }
    __syncthreads();

    bf16x8 a[4], bb[4];
#pragma unroll
    for (int i = 0; i < 4; i++)
      a[i] = __builtin_bit_cast(bf16x8,
          *(const s16x8*)&As[(wr * 64 + i * 16 + m16) * BK + quad * 8]);
#pragma unroll
    for (int j = 0; j < 4; j++)
      bb[j] = __builtin_bit_cast(bf16x8,
          *(const s16x8*)&Bs[(wc * 64 + j * 16 + m16) * BK + quad * 8]);
#pragma unroll
    for (int i = 0; i < 4; i++)
#pragma unroll
      for (int j = 0; j < 4; j++)
        acc[i][j] = __builtin_amdgcn_mfma_f32_16x16x32_bf16(a[i], bb[j], acc[i][j], 0, 0, 0);
    __syncthreads();
  }

#pragma unroll
  for (int j = 0; j < 4; j++) {
    int col = col0 + wc * 64 + j * 16 + m16;
    float s = 0.f, q = 0.f;
#pragma unroll
    for (int i = 0; i < 4; i++)
#pragma unroll
      for (int r = 0; r < 4; r++) {
        float v = acc[i][j][r];
        Y1[(size_t)(row0 + wr * 64 + i * 16 + quad * 4 + r) * C1 + col] = f2bf(v);
        s += v; q = fmaf(v, v, q);
      }
    s += __shfl_xor(s, 16, 64); s += __shfl_xor(s, 32, 64);
    q += __shfl_xor(q, 16, 64); q += __shfl_xor(q, 32, 64);
    if (quad == 0) {
      atomicAdd(&sum1[col], s);
      atomicAdd(&sumsq1[col], q);
    }
  }
}

// ---------------------------------------------------------------------------
// GEMM2, 4-wave 128x128 tile: X2 = relu(bn1(Y1)) fused in reg-staged A.
// BN1 coefficients computed in-kernel from atomic sums (gemm1 complete by
// stream order). BN2 stats via atomics. grid = NRB.
// ---------------------------------------------------------------------------
__global__ __launch_bounds__(256) void gemm2_mw(
    const unsigned short* __restrict__ Y1,   // [BN_TOTAL][C1] bf16
    const float* __restrict__ g1, const float* __restrict__ beta1,
    const float* __restrict__ sum1, const float* __restrict__ sumsq1,
    const unsigned short* __restrict__ W2h,  // [C2][C1] bf16
    const float* __restrict__ bias,
    unsigned short* __restrict__ Y2,         // [BN_TOTAL][C2] bf16
    float* __restrict__ sum2, float* __restrict__ sumsq2) {
  __shared__ __align__(16) unsigned short As[BM * BK];
  __shared__ __align__(16) unsigned short Bs[BM * BK];
  __shared__ float scs[C1], shs[C1];
  int tid = threadIdx.x;
  int lane = tid & 63, w = tid >> 6;
  int wr = w >> 1, wc = w & 1;
  int m16 = lane & 15, quad = lane >> 4;
  int rb = blockIdx.x;
  int row0 = rb * BM, col0 = 0;
  int srow = lane >> 2, scol8 = (lane & 3) * 8;

  {  // compute BN1 scale/shift for this thread's channel (C1 == blockDim)
    const float invBN = 1.0f / (float)BN_TOTAL;
    float mean = sum1[tid] * invBN;
    float var = sumsq1[tid] * invBN - mean * mean;
    float sc = g1[tid] / sqrtf(var + 1e-5f);
    scs[tid] = sc;
    shs[tid] = beta1[tid] - mean * sc;
  }

  f32x4 acc[4][4];
#pragma unroll
  for (int j = 0; j < 4; j++) {
    float bj = bias[col0 + wc * 64 + j * 16 + m16];
#pragma unroll
    for (int i = 0; i < 4; i++) acc[i][j] = f32x4{bj, bj, bj, bj};
  }
  __syncthreads();

  for (int k0 = 0; k0 < C1; k0 += BK) {
#pragma unroll
    for (int kq = 0; kq < 2; kq++) {
      int ar = 32 * w + 16 * kq + srow;
      int lb = __builtin_amdgcn_readfirstlane((32 * w + 16 * kq) * BK);
      gld_lds16(&W2h[(size_t)(col0 + ar) * C1 + k0 + scol8], &Bs[lb]);
      // A tile: load Y1, apply BN1+ReLU, write LDS
      s16x8 v = *(const s16x8*)&Y1[(size_t)(row0 + ar) * C1 + k0 + scol8];
      unsigned short ov[8];
#pragma unroll
      for (int e = 0; e < 8; e++) {
        float x = bf2f((unsigned short)v[e]);
        float y = fmaxf(fmaf(x, scs[k0 + scol8 + e], shs[k0 + scol8 + e]), 0.f);
        ov[e] = f2bf(y);
      }
      *(s16x8*)&As[ar * BK + scol8] = *(const s16x8*)ov;
    }
    __syncthreads();

    bf16x8 a[4], bb[4];
#pragma unroll
    for (int i = 0; i < 4; i++)
      a[i] = __builtin_bit_cast(bf16x8,
          *(const s16x8*)&As[(wr * 64 + i * 16 + m16) * BK + quad * 8]);
#pragma unroll
    for (int j = 0; j < 4; j++)
      bb[j] = __builtin_bit_cast(bf16x8,
          *(const s16x8*)&Bs[(wc * 64 + j * 16 + m16) * BK + quad * 8]);
#pragma unroll
    for (int i = 0; i < 4; i++)
#pragma unroll
      for (int j = 0; j < 4; j++)
        acc[i][j] = __builtin_amdgcn_mfma_f32_16x16x32_bf16(a[i], bb[j], acc[i][j], 0, 0, 0);
    __syncthreads();
  }

#pragma unroll
  for (int j = 0; j < 4; j++) {
    int col = col0 + wc * 64 + j * 16 + m16;
    float s = 0.f, q = 0.f;
#pragma unroll
    for (int i = 0; i < 4; i++)
#pragma unroll
      for (int r = 0; r < 4; r++) {
        float v = acc[i][j][r];
        Y2[(size_t)(row0 + wr * 64 + i * 16 + quad * 4 + r) * C2 + col] = f2bf(v);
        s += v; q = fmaf(v, v, q);
      }
    s += __shfl_xor(s, 16, 64); s += __shfl_xor(s, 32, 64);
    q += __shfl_xor(q, 16, 64); q += __shfl_xor(q, 32, 64);
    if (quad == 0) {
      atomicAdd(&sum2[col], s);
      atomicAdd(&sumsq2[col], q);
    }
  }
}

// ---------------------------------------------------------------------------
// Final: out[b][c][n] = relu(bn2(Y2)) transposed, fp32 out.
// BN2 coefficients computed inline from atomic sums.
// ---------------------------------------------------------------------------
__global__ void final_kernel(const unsigned short* __restrict__ Y2,
                             const float* __restrict__ sum2,
                             const float* __restrict__ sumsq2,
                             const float* __restrict__ g2,
                             const float* __restrict__ beta2,
                             float* __restrict__ out) {
  __shared__ float tile[32][33];
  int b = blockIdx.z;
  int n0 = blockIdx.x * 32;
  int c0 = blockIdx.y * 32;
  int tx = threadIdx.x, ty = threadIdx.y;
  int c = c0 + tx;
  const float invBN = 1.0f / (float)BN_TOTAL;
  float mean = sum2[c] * invBN;
  float var = sumsq2[c] * invBN - mean * mean;
  float sc = g2[c] / sqrtf(var + 1e-5f);
  float sh = beta2[c] - mean * sc;
#pragma unroll
  for (int i = 0; i < 32; i += 8) {
    int n = n0 + ty + i;
    float v = bf2f(Y2[((size_t)b * NPT + n) * C2 + c0 + tx]);
    tile[ty + i][tx] = fmaxf(fmaf(v, sc, sh), 0.f);
  }
  __syncthreads();
#pragma unroll
  for (int i = 0; i < 32; i += 8) {
    int cc = c0 + ty + i;
    out[((size_t)b * C2 + cc) * NPT + n0 + tx] = tile[tx][ty + i];
  }
}

// ---------------------------------------------------------------------------
extern "C" void kernel_launch(void* const* d_in, const int* in_sizes, int n_in,
                              void* d_out, int out_size, void* d_ws, size_t ws_size,
                              hipStream_t stream) {
  (void)in_sizes; (void)n_in; (void)out_size; (void)ws_size;
  const float* pos   = (const float*)d_in[0];
  const float* spos  = (const float*)d_in[1];
  const float* skip  = (const float*)d_in[2];
  const float* sfeat = (const float*)d_in[3];
  const float* W1    = (const float*)d_in[4];
  const float* b1    = (const float*)d_in[5];
  const float* g1    = (const float*)d_in[6];
  const float* beta1 = (const float*)d_in[7];
  const float* W2    = (const float*)d_in[8];
  const float* b2    = (const float*)d_in[9];
  const float* g2    = (const float*)d_in[10];
  const float* beta2 = (const float*)d_in[11];
  float* out = (float*)d_out;

  float* ws = (float*)d_ws;
  size_t off = 0;
  float* sfeatT  = ws + off; off += (size_t)BATCH * NSMP * D2C;
  unsigned short* featB = (unsigned short*)(ws + off); off += (size_t)BN_TOTAL * CIN / 2;
  unsigned short* Y1    = (unsigned short*)(ws + off); off += (size_t)BN_TOTAL * C1 / 2;
  unsigned short* Y2    = (unsigned short*)(ws + off); off += (size_t)BN_TOTAL * C2 / 2;
  unsigned short* W1h   = (unsigned short*)(ws + off); off += (size_t)C1 * CIN / 2;
  unsigned short* W2h   = (unsigned short*)(ws + off); off += (size_t)C2 * C1 / 2;
  float* sposI   = ws + off; off += (size_t)BATCH * NSMP * 3;
  float4* qs4    = (float4*)(ws + off); off += (size_t)BATCH * NSMP * 4;
  float* stats   = ws + off; off += 1024;
  float* sum1   = stats;        // [256]
  float* sumsq1 = stats + 256;  // [256]
  float* sum2   = stats + 512;  // [128]
  float* sumsq2 = stats + 640;  // [128]

  prep_all<<<PT_T + PT_S + PT_M, 256, 0, stream>>>(
      sfeat, sfeatT, skip, featB, spos, sposI, qs4, W1, W1h, W2, W2h, stats);

  knn_all<<<BN_TOTAL / 256, 512, 0, stream>>>(pos, qs4, sposI, sfeatT, featB);

  gemm1_mw<<<dim3(C1 / BM, NRB), 256, 0, stream>>>(
      featB, W1h, b1, Y1, sum1, sumsq1);

  gemm2_mw<<<NRB, 256, 0, stream>>>(
      Y1, g1, beta1, sum1, sumsq1, W2h, b2, Y2, sum2, sumsq2);

  final_kernel<<<dim3(NPT / 32, C2 / 32, BATCH), dim3(32, 8), 0, stream>>>(
      Y2, sum2, sumsq2, g2, beta2, out);
}

// Round 7
// 287.749 us; speedup vs baseline: 2.0906x; 1.0133x over previous
//
#include <hip/hip_runtime.h>

// Problem constants
constexpr int BATCH = 8;
constexpr int NPT   = 8192;   // N points
constexpr int NSMP  = 2048;   // S sampled points
constexpr int D1C   = 128;    // skip feature channels
constexpr int D2C   = 256;    // sampled feature channels
constexpr int CIN   = 384;    // D1C + D2C
constexpr int C1    = 256;    // layer-1 out channels
constexpr int C2    = 128;    // layer-2 out channels
constexpr int BN_TOTAL = BATCH * NPT;  // 65536 rows

// Multi-wave GEMM tiling: 4 waves (256 thr), 128x128 tile, BK=32 (m97 structure)
constexpr int BM = 128, BK = 32;
constexpr int NRB = BN_TOTAL / BM;   // 512 row-blocks

typedef __bf16 bf16x8 __attribute__((ext_vector_type(8)));
typedef short  s16x8  __attribute__((ext_vector_type(8)));
typedef float  f32x4  __attribute__((ext_vector_type(4)));
typedef unsigned short u16x4 __attribute__((ext_vector_type(4)));

__device__ __forceinline__ unsigned short f2bf(float x) {
  unsigned u = __builtin_bit_cast(unsigned, x);
  u += 0x7fffu + ((u >> 16) & 1u);   // round-to-nearest-even
  return (unsigned short)(u >> 16);
}
__device__ __forceinline__ float bf2f(unsigned short h) {
  return __builtin_bit_cast(float, (unsigned)h << 16);
}

// async global -> LDS, 16 B per lane; lds dest wave-uniform base + lane*16
__device__ __forceinline__ void gld_lds16(const void* g, void* l) {
  __builtin_amdgcn_global_load_lds(
      (const __attribute__((address_space(1))) void*)g,
      (__attribute__((address_space(3))) void*)l, 16, 0, 0);
}

// ---------------------------------------------------------------------------
// prep_all: fused transpose(sfeat->sfeatT) + skip->featB + W casts + spos pack
// + BN-stat zeroing. Role selected by block-index range. 5 graph nodes total.
// R5 lesson: NO __threadfence cross-block reductions on CDNA4 (L2 writeback
// storm); BN stats go through device-scope float atomics (G12).
// ---------------------------------------------------------------------------
constexpr int PT_T = (NSMP / 32) * (D2C / 32) * BATCH;  // 4096 transpose blocks
constexpr int PT_S = (NPT / 32) * (D1C / 32) * BATCH;   // 8192 skip blocks
constexpr int PT_M = (C1 * CIN + 255) / 256;            // 384 misc blocks

__global__ __launch_bounds__(256) void prep_all(
    const float* __restrict__ sfeat, float* __restrict__ sfeatT,
    const float* __restrict__ skip, unsigned short* __restrict__ featB,
    const float* __restrict__ spos, float* __restrict__ sposI,
    float4* __restrict__ qs4,
    const float* __restrict__ W1, unsigned short* __restrict__ W1h,
    const float* __restrict__ W2, unsigned short* __restrict__ W2h,
    float* __restrict__ stats) {   // [0..255]=sum1 [256..511]=sumsq1
                                   // [512..639]=sum2 [640..767]=sumsq2
  __shared__ float tile[32][33];
  int bid = blockIdx.x, tid = threadIdx.x;
  int tx = tid & 31, ty = tid >> 5;
  if (bid < PT_T) {
    // transpose sfeat [B, D2C, NSMP] -> sfeatT [B, NSMP, D2C]
    int z = bid >> 9;           // 512 blocks per batch
    int r = bid & 511;
    int c0 = (r & 63) * 32;     // over NSMP
    int r0 = (r >> 6) * 32;     // over D2C
    const float* inb = sfeat + (size_t)z * D2C * NSMP;
    float* outb = sfeatT + (size_t)z * NSMP * D2C;
#pragma unroll
    for (int i = 0; i < 32; i += 8)
      tile[ty + i][tx] = inb[(size_t)(r0 + ty + i) * NSMP + c0 + tx];
    __syncthreads();
#pragma unroll
    for (int i = 0; i < 32; i += 8)
      outb[(size_t)(c0 + ty + i) * D2C + r0 + tx] = tile[tx][ty + i];
  } else if (bid < PT_T + PT_S) {
    // skip [B, D1C, NPT] -> featB[.][0..127] bf16
    int id = bid - PT_T;
    int z = id >> 10;           // 1024 blocks per batch
    int r = id & 1023;
    int n0 = (r & 255) * 32;    // over NPT
    int d0 = (r >> 8) * 32;     // over D1C
#pragma unroll
    for (int i = 0; i < 32; i += 8)
      tile[ty + i][tx] = skip[((size_t)z * D1C + d0 + ty + i) * NPT + n0 + tx];
    __syncthreads();
#pragma unroll
    for (int i = 0; i < 32; i += 8) {
      int n = n0 + ty + i;
      featB[((size_t)z * NPT + n) * CIN + d0 + tx] = f2bf(tile[tx][ty + i]);
    }
  } else {
    int g = (bid - PT_T - PT_S) * 256 + tid;
    if (g < 768) stats[g] = 0.f;
    if (g < C1 * CIN) W1h[g] = f2bf(W1[g]);
    if (g < C2 * C1)  W2h[g] = f2bf(W2[g]);
    if (g < BATCH * NSMP) {
      int b = g >> 11, s = g & (NSMP - 1);
      const float* sp = spos + (size_t)b * 3 * NSMP;
      float x = sp[s], y = sp[NSMP + s], z = sp[2 * NSMP + s];
      sposI[(size_t)g * 3 + 0] = x;
      sposI[(size_t)g * 3 + 1] = y;
      sposI[(size_t)g * 3 + 2] = z;
      qs4[g] = make_float4(-2.f * x, -2.f * y, -2.f * z,
                           fmaf(x, x, fmaf(y, y, z * z)));
    }
  }
}

// ---------------------------------------------------------------------------
// knn_all: scan + certification + in-block exact fp64 fallback + interp.
// 256 blocks x 512 thr; each block owns 256 points; each LANE owns 4 points.
// R6 lessons applied:
//  - XCD swizzle (b = blk&7): all blocks of batch b land on XCD b (round-
//    robin dispatch, m09) -> qs4/sposI/sfeatT slices are XCD-L2-resident;
//    kills the 79MB HBM refetch seen in R6.
//  - Candidate delivery via LDS + ds_read_b128 broadcast: per-wave one-time
//    stage of its 256-cand segment (4x global_load_lds w16). DS cost
//    256x12cy x8 waves = 10us/CU < VALU floor 17us; removes the ~16cy/instr
//    TA port cost of per-lane VMEM (R4) entirely.
//  - mk results reuse the wave's own dead qs segment (exact 4KB) -> 39KB LDS.
// R2 lesson: keep +pp (packed key = true small distance near zero).
// ---------------------------------------------------------------------------
constexpr int KWAVES = 8;
constexpr int SEGK = NSMP / KWAVES;  // 256 candidates per wave

__device__ __forceinline__ void ins_med3(float kf, float& k0, float& k1,
                                         float& k2, float& k3) {
  float o0 = k0, o1 = k1, o2 = k2;
  k0 = fminf(kf, o0);
  k1 = __builtin_amdgcn_fmed3f(kf, o0, o1);
  k2 = __builtin_amdgcn_fmed3f(kf, o1, o2);
  k3 = __builtin_amdgcn_fmed3f(kf, o2, k3);
}

__device__ __forceinline__ bool dless(double d, int i, double D, int I) {
  return d < D || (d == D && i < I);
}
__device__ __forceinline__ void dins3(double d, int i,
                                      double& b0, double& b1, double& b2,
                                      int& i0, int& i1, int& i2) {
  if (dless(d, i, b2, i2)) {
    if (dless(d, i, b1, i1)) {
      b2 = b1; i2 = i1;
      if (dless(d, i, b0, i0)) { b1 = b0; i1 = i0; b0 = d; i0 = i; }
      else                     { b1 = d; i1 = i; }
    } else { b2 = d; i2 = i; }
  }
}

__global__ __launch_bounds__(512, 2) void knn_all(
    const float* __restrict__ pos,    // [B,3,NPT]
    const float4* __restrict__ qs4g,  // [B,NSMP] transformed
    const float* __restrict__ sposI,  // [B,NSMP,3] original (fp64 paths)
    const float* __restrict__ sfeatT, // [B,NSMP,D2C]
    unsigned short* __restrict__ featB) {
  // qs region (32 KB) doubles as mk storage: wave w's mk (4 KB) overwrites
  // its own finished 4 KB candidate segment — no cross-wave hazard.
  __shared__ __align__(16) unsigned char smem[NSMP * 16];
  float4* qs  = (float4*)smem;
  float*  mkf = (float*)smem;
#define MKF(w, sl, m, l) mkf[(w) * 1024 + ((sl) * 4 + (m)) * 64 + (l)]
  __shared__ int   il[256][3];            // 3 KB  per-point neighbor idx
  __shared__ float wl[256][3];            // 3 KB  per-point weights
  __shared__ int   fl[256];               // 1 KB  flagged-point list
  __shared__ int   fcnt;

  int tid = threadIdx.x;
  int wave = tid >> 6, lane = tid & 63;
  int blk = blockIdx.x;
  int b = blk & 7;               // XCD swizzle: batch b -> XCD b
  int n0 = (blk >> 3) << 8;      // 32 chunks of 256 points per batch

  if (tid == 0) fcnt = 0;

  const float* pb = pos + (size_t)b * 3 * NPT;
  float px[4], py[4], pz[4], pp[4];
#pragma unroll
  for (int m = 0; m < 4; m++) {
    int n = n0 + (m << 6) + lane;
    px[m] = pb[n]; py[m] = pb[NPT + n]; pz[m] = pb[2 * NPT + n];
    pp[m] = fmaf(px[m], px[m], fmaf(py[m], py[m], pz[m] * pz[m]));
  }

  const float INF = __builtin_inff();
  float k0[4], k1[4], k2[4], k3[4];
#pragma unroll
  for (int m = 0; m < 4; m++) { k0[m] = INF; k1[m] = INF; k2[m] = INF; k3[m] = INF; }

  int s0 = wave * SEGK;
  // stage this wave's candidate segment: 4 x (64 lanes x 16 B) = 4 KB
  const float4* qsrc = qs4g + (size_t)b * NSMP;
#pragma unroll
  for (int r = 0; r < 4; r++)
    gld_lds16(&qsrc[s0 + r * 64 + lane], &qs[s0 + r * 64]);
  __syncthreads();

#define KSTEP4(Q, SS)                                                        \
  {                                                                          \
    _Pragma("unroll")                                                        \
    for (int m_ = 0; m_ < 4; m_++) {                                         \
      float tt = (Q).w + pp[m_];  /* recenter: d small near neighbors */     \
      float d_ = fmaf(px[m_], (Q).x,                                         \
                      fmaf(py[m_], (Q).y, fmaf(pz[m_], (Q).z, tt)));         \
      unsigned ki_ = (__builtin_bit_cast(unsigned, d_) & 0xFFFFF800u) |      \
                     (unsigned)(SS);                                         \
      ins_med3(__builtin_bit_cast(float, ki_), k0[m_], k1[m_], k2[m_], k3[m_]); \
    }                                                                        \
  }

  for (int t = 0; t < SEGK; t += 8) {
    float4 qv[8];
#pragma unroll
    for (int u = 0; u < 8; u++) qv[u] = qs[s0 + t + u];  // broadcast ds_read
#pragma unroll
    for (int u = 0; u < 8; u++) KSTEP4(qv[u], s0 + t + u)
  }
#undef KSTEP4

  // write per-wave top-4 into own (dead) segment
#pragma unroll
  for (int m = 0; m < 4; m++) {
    MKF(wave, 0, m, lane) = k0[m];
    MKF(wave, 1, m, lane) = k1[m];
    MKF(wave, 2, m, lane) = k2[m];
    MKF(wave, 3, m, lane) = k3[m];
  }
  __syncthreads();

  // ---- per-point finalize (256 threads), flag + fp64 weights into LDS ----
  if (tid < 256) {
    int pm = tid >> 6, pl = tid & 63;
    float K0 = INF, K1 = INF, K2 = INF, K3 = INF;
#pragma unroll
    for (int w = 0; w < KWAVES; w++)
#pragma unroll
      for (int sl = 0; sl < 4; sl++)
        ins_med3(MKF(w, sl, pm, pl), K0, K1, K2, K3);

    int I0 = (int)(__builtin_bit_cast(unsigned, K0) & 0x7FFu);
    int I1 = (int)(__builtin_bit_cast(unsigned, K1) & 0x7FFu);
    int I2 = (int)(__builtin_bit_cast(unsigned, K2) & 0x7FFu);
    float d2m = __builtin_bit_cast(float, __builtin_bit_cast(unsigned, K2) & 0xFFFFF800u);
    float d3m = __builtin_bit_cast(float, __builtin_bit_cast(unsigned, K3) & 0xFFFFF800u);
    bool flag = (d3m - d2m) < 2e-3f * fmaxf(d3m, 0.f) + 1e-5f;
    if (flag) {
      int slot = atomicAdd(&fcnt, 1);
      fl[slot] = tid;
    }
    int n = n0 + tid;
    const float* q = sposI + (size_t)b * 3 * NSMP;
    double pxd = (double)pb[n], pyd = (double)pb[NPT + n], pzd = (double)pb[2 * NPT + n];
    double dd[3]; int II[3] = {I0, I1, I2};
#pragma unroll
    for (int k = 0; k < 3; k++) {
      double dx = pxd - (double)q[3 * II[k]];
      double dy = pyd - (double)q[3 * II[k] + 1];
      double dz = pzd - (double)q[3 * II[k] + 2];
      dd[k] = dx * dx + dy * dy + dz * dz;
    }
    double w0 = 1.0 / (dd[0] + 1e-8);
    double w1 = 1.0 / (dd[1] + 1e-8);
    double w2 = 1.0 / (dd[2] + 1e-8);
    double inv = 1.0 / (w0 + w1 + w2);
    il[tid][0] = I0; il[tid][1] = I1; il[tid][2] = I2;
    wl[tid][0] = (float)(w0 * inv);
    wl[tid][1] = (float)(w1 * inv);
    wl[tid][2] = (float)(w2 * inv);
  }
  __syncthreads();

  // ---- exact fp64 fallback for flagged points, one wave per point ----
  int fc = fcnt;
  for (int t = wave; t < fc; t += KWAVES) {
    int P = fl[t];
    int n = n0 + P;
    double pxd = (double)pb[n], pyd = (double)pb[NPT + n], pzd = (double)pb[2 * NPT + n];
    const float* q = sposI + (size_t)b * 3 * NSMP;
    double b0 = 1e300, b1 = 1e300, b2 = 1e300;
    int i0 = 0x7FFFFFFF, i1 = 0x7FFFFFFF, i2 = 0x7FFFFFFF;
    for (int s = lane; s < NSMP; s += 64) {
      double dx = pxd - (double)q[3 * s];
      double dy = pyd - (double)q[3 * s + 1];
      double dz = pzd - (double)q[3 * s + 2];
      double d = dx * dx + dy * dy + dz * dz;
      dins3(d, s, b0, b1, b2, i0, i1, i2);
    }
#pragma unroll
    for (int m = 1; m < 64; m <<= 1) {
      double o0 = __shfl_xor(b0, m, 64), o1 = __shfl_xor(b1, m, 64), o2 = __shfl_xor(b2, m, 64);
      int    j0 = __shfl_xor(i0, m, 64), j1 = __shfl_xor(i1, m, 64), j2 = __shfl_xor(i2, m, 64);
      dins3(o0, j0, b0, b1, b2, i0, i1, i2);
      dins3(o1, j1, b0, b1, b2, i0, i1, i2);
      dins3(o2, j2, b0, b1, b2, i0, i1, i2);
    }
    if (lane == 0) {
      double w0 = 1.0 / (b0 + 1e-8);
      double w1 = 1.0 / (b1 + 1e-8);
      double w2 = 1.0 / (b2 + 1e-8);
      double inv = 1.0 / (w0 + w1 + w2);
      il[P][0] = i0; il[P][1] = i1; il[P][2] = i2;
      wl[P][0] = (float)(w0 * inv);
      wl[P][1] = (float)(w1 * inv);
      wl[P][2] = (float)(w2 * inv);
    }
  }
  __syncthreads();

  // ---- interp: each wave handles 32 points; lane covers 4 channels ----
  // sfeatT batch slice (2 MB) is XCD-L2-resident thanks to the swizzle.
  const float* base = sfeatT + (size_t)b * NSMP * D2C;
  for (int i = 0; i < 32; i++) {
    int P = (wave << 5) + i;
    int i0 = il[P][0], i1 = il[P][1], i2 = il[P][2];
    float w0 = wl[P][0], w1 = wl[P][1], w2 = wl[P][2];
    float4 v0 = *(const float4*)&base[(size_t)i0 * D2C + (lane << 2)];
    float4 v1 = *(const float4*)&base[(size_t)i1 * D2C + (lane << 2)];
    float4 v2 = *(const float4*)&base[(size_t)i2 * D2C + (lane << 2)];
    u16x4 o;
    o[0] = f2bf(w0 * v0.x + w1 * v1.x + w2 * v2.x);
    o[1] = f2bf(w0 * v0.y + w1 * v1.y + w2 * v2.y);
    o[2] = f2bf(w0 * v0.z + w1 * v1.z + w2 * v2.z);
    o[3] = f2bf(w0 * v0.w + w1 * v1.w + w2 * v2.w);
    *(u16x4*)&featB[((size_t)b * NPT + n0 + P) * CIN + D1C + (lane << 2)] = o;
  }
#undef MKF
}

// ---------------------------------------------------------------------------
// GEMM1, 4-wave 128x128 tile (m97 structure): Y1 = featB @ W1^T + b1.
// BN1 stats via device-scope float atomics (no fence, no extra node).
// ---------------------------------------------------------------------------
__global__ __launch_bounds__(256) void gemm1_mw(
    const unsigned short* __restrict__ featB,  // [BN_TOTAL][CIN] bf16
    const unsigned short* __restrict__ W1h,    // [C1][CIN] bf16
    const float* __restrict__ bias,
    unsigned short* __restrict__ Y1,           // [BN_TOTAL][C1] bf16
    float* __restrict__ sum1,                  // [C1]
    float* __restrict__ sumsq1) {              // [C1]
  __shared__ __align__(16) unsigned short As[BM * BK];  // 8 KB
  __shared__ __align__(16) unsigned short Bs[BM * BK];  // 8 KB
  int tid = threadIdx.x;
  int lane = tid & 63, w = tid >> 6;
  int wr = w >> 1, wc = w & 1;
  int m16 = lane & 15, quad = lane >> 4;
  int cb = blockIdx.x, rb = blockIdx.y;
  int row0 = rb * BM, col0 = cb * BM;
  int srow = lane >> 2, scol8 = (lane & 3) * 8;

  f32x4 acc[4][4];
#pragma unroll
  for (int j = 0; j < 4; j++) {
    float bj = bias[col0 + wc * 64 + j * 16 + m16];
#pragma unroll
    for (int i = 0; i < 4; i++) acc[i][j] = f32x4{bj, bj, bj, bj};
  }

  for (int k0 = 0; k0 < CIN; k0 += BK) {
#pragma unroll
    for (int kq = 0; kq < 2; kq++) {
      int ar = 32 * w + 16 * kq + srow;
      int lb = __builtin_amdgcn_readfirstlane((32 * w + 16 * kq) * BK);
      gld_lds16(&featB[(size_t)(row0 + ar) * CIN + k0 + scol8], &As[lb]);
      gld_lds16(&W1h[(size_t)(col0 + ar) * CIN + k0 + scol8], &Bs[lb]);
    }
    __syncthreads();

    bf16x8 a[4], bb[4];
#pragma unroll
    for (int i = 0; i < 4; i++)
      a[i] = __builtin_bit_cast(bf16x8,
          *(const s16x8*)&As[(wr * 64 + i * 16 + m16) * BK + quad * 8]);
#pragma unroll
    for (int j = 0; j < 4; j++)
      bb[j] = __builtin_bit_cast(bf16x8,
          *(const s16x8*)&Bs[(wc * 64 + j * 16 + m16) * BK + quad * 8]);
#pragma unroll
    for (int i = 0; i < 4; i++)
#pragma unroll
      for (int j = 0; j < 4; j++)
        acc[i][j] = __builtin_amdgcn_mfma_f32_16x16x32_bf16(a[i], bb[j], acc[i][j], 0, 0, 0);
    __syncthreads();
  }

#pragma unroll
  for (int j = 0; j < 4; j++) {
    int col = col0 + wc * 64 + j * 16 + m16;
    float s = 0.f, q = 0.f;
#pragma unroll
    for (int i = 0; i < 4; i++)
#pragma unroll
      for (int r = 0; r < 4; r++) {
        float v = acc[i][j][r];
        Y1[(size_t)(row0 + wr * 64 + i * 16 + quad * 4 + r) * C1 + col] = f2bf(v);
        s += v; q = fmaf(v, v, q);
      }
    s += __shfl_xor(s, 16, 64); s += __shfl_xor(s, 32, 64);
    q += __shfl_xor(q, 16, 64); q += __shfl_xor(q, 32, 64);
    if (quad == 0) {
      atomicAdd(&sum1[col], s);
      atomicAdd(&sumsq1[col], q);
    }
  }
}

// ---------------------------------------------------------------------------
// GEMM2, 4-wave 128x128 tile: X2 = relu(bn1(Y1)) fused in reg-staged A.
// BN1 coefficients computed in-kernel from atomic sums (gemm1 complete by
// stream order). BN2 stats via atomics. grid = NRB.
// ---------------------------------------------------------------------------
__global__ __launch_bounds__(256) void gemm2_mw(
    const unsigned short* __restrict__ Y1,   // [BN_TOTAL][C1] bf16
    const float* __restrict__ g1, const float* __restrict__ beta1,
    const float* __restrict__ sum1, const float* __restrict__ sumsq1,
    const unsigned short* __restrict__ W2h,  // [C2][C1] bf16
    const float* __restrict__ bias,
    unsigned short* __restrict__ Y2,         // [BN_TOTAL][C2] bf16
    float* __restrict__ sum2, float* __restrict__ sumsq2) {
  __shared__ __align__(16) unsigned short As[BM * BK];
  __shared__ __align__(16) unsigned short Bs[BM * BK];
  __shared__ float scs[C1], shs[C1];
  int tid = threadIdx.x;
  int lane = tid & 63, w = tid >> 6;
  int wr = w >> 1, wc = w & 1;
  int m16 = lane & 15, quad = lane >> 4;
  int rb = blockIdx.x;
  int row0 = rb * BM, col0 = 0;
  int srow = lane >> 2, scol8 = (lane & 3) * 8;

  {  // compute BN1 scale/shift for this thread's channel (C1 == blockDim)
    const float invBN = 1.0f / (float)BN_TOTAL;
    float mean = sum1[tid] * invBN;
    float var = sumsq1[tid] * invBN - mean * mean;
    float sc = g1[tid] / sqrtf(var + 1e-5f);
    scs[tid] = sc;
    shs[tid] = beta1[tid] - mean * sc;
  }

  f32x4 acc[4][4];
#pragma unroll
  for (int j = 0; j < 4; j++) {
    float bj = bias[col0 + wc * 64 + j * 16 + m16];
#pragma unroll
    for (int i = 0; i < 4; i++) acc[i][j] = f32x4{bj, bj, bj, bj};
  }
  __syncthreads();

  for (int k0 = 0; k0 < C1; k0 += BK) {
#pragma unroll
    for (int kq = 0; kq < 2; kq++) {
      int ar = 32 * w + 16 * kq + srow;
      int lb = __builtin_amdgcn_readfirstlane((32 * w + 16 * kq) * BK);
      gld_lds16(&W2h[(size_t)(col0 + ar) * C1 + k0 + scol8], &Bs[lb]);
      // A tile: load Y1, apply BN1+ReLU, write LDS
      s16x8 v = *(const s16x8*)&Y1[(size_t)(row0 + ar) * C1 + k0 + scol8];
      unsigned short ov[8];
#pragma unroll
      for (int e = 0; e < 8; e++) {
        float x = bf2f((unsigned short)v[e]);
        float y = fmaxf(fmaf(x, scs[k0 + scol8 + e], shs[k0 + scol8 + e]), 0.f);
        ov[e] = f2bf(y);
      }
      *(s16x8*)&As[ar * BK + scol8] = *(const s16x8*)ov;
    }
    __syncthreads();

    bf16x8 a[4], bb[4];
#pragma unroll
    for (int i = 0; i < 4; i++)
      a[i] = __builtin_bit_cast(bf16x8,
          *(const s16x8*)&As[(wr * 64 + i * 16 + m16) * BK + quad * 8]);
#pragma unroll
    for (int j = 0; j < 4; j++)
      bb[j] = __builtin_bit_cast(bf16x8,
          *(const s16x8*)&Bs[(wc * 64 + j * 16 + m16) * BK + quad * 8]);
#pragma unroll
    for (int i = 0; i < 4; i++)
#pragma unroll
      for (int j = 0; j < 4; j++)
        acc[i][j] = __builtin_amdgcn_mfma_f32_16x16x32_bf16(a[i], bb[j], acc[i][j], 0, 0, 0);
    __syncthreads();
  }

#pragma unroll
  for (int j = 0; j < 4; j++) {
    int col = col0 + wc * 64 + j * 16 + m16;
    float s = 0.f, q = 0.f;
#pragma unroll
    for (int i = 0; i < 4; i++)
#pragma unroll
      for (int r = 0; r < 4; r++) {
        float v = acc[i][j][r];
        Y2[(size_t)(row0 + wr * 64 + i * 16 + quad * 4 + r) * C2 + col] = f2bf(v);
        s += v; q = fmaf(v, v, q);
      }
    s += __shfl_xor(s, 16, 64); s += __shfl_xor(s, 32, 64);
    q += __shfl_xor(q, 16, 64); q += __shfl_xor(q, 32, 64);
    if (quad == 0) {
      atomicAdd(&sum2[col], s);
      atomicAdd(&sumsq2[col], q);
    }
  }
}

// ---------------------------------------------------------------------------
// Final: out[b][c][n] = relu(bn2(Y2)) transposed, fp32 out.
// BN2 coefficients computed inline from atomic sums.
// ---------------------------------------------------------------------------
__global__ void final_kernel(const unsigned short* __restrict__ Y2,
                             const float* __restrict__ sum2,
                             const float* __restrict__ sumsq2,
                             const float* __restrict__ g2,
                             const float* __restrict__ beta2,
                             float* __restrict__ out) {
  __shared__ float tile[32][33];
  int b = blockIdx.z;
  int n0 = blockIdx.x * 32;
  int c0 = blockIdx.y * 32;
  int tx = threadIdx.x, ty = threadIdx.y;
  int c = c0 + tx;
  const float invBN = 1.0f / (float)BN_TOTAL;
  float mean = sum2[c] * invBN;
  float var = sumsq2[c] * invBN - mean * mean;
  float sc = g2[c] / sqrtf(var + 1e-5f);
  float sh = beta2[c] - mean * sc;
#pragma unroll
  for (int i = 0; i < 32; i += 8) {
    int n = n0 + ty + i;
    float v = bf2f(Y2[((size_t)b * NPT + n) * C2 + c0 + tx]);
    tile[ty + i][tx] = fmaxf(fmaf(v, sc, sh), 0.f);
  }
  __syncthreads();
#pragma unroll
  for (int i = 0; i < 32; i += 8) {
    int cc = c0 + ty + i;
    out[((size_t)b * C2 + cc) * NPT + n0 + tx] = tile[tx][ty + i];
  }
}

// ---------------------------------------------------------------------------
extern "C" void kernel_launch(void* const* d_in, const int* in_sizes, int n_in,
                              void* d_out, int out_size, void* d_ws, size_t ws_size,
                              hipStream_t stream) {
  (void)in_sizes; (void)n_in; (void)out_size; (void)ws_size;
  const float* pos   = (const float*)d_in[0];
  const float* spos  = (const float*)d_in[1];
  const float* skip  = (const float*)d_in[2];
  const float* sfeat = (const float*)d_in[3];
  const float* W1    = (const float*)d_in[4];
  const float* b1    = (const float*)d_in[5];
  const float* g1    = (const float*)d_in[6];
  const float* beta1 = (const float*)d_in[7];
  const float* W2    = (const float*)d_in[8];
  const float* b2    = (const float*)d_in[9];
  const float* g2    = (const float*)d_in[10];
  const float* beta2 = (const float*)d_in[11];
  float* out = (float*)d_out;

  float* ws = (float*)d_ws;
  size_t off = 0;
  float* sfeatT  = ws + off; off += (size_t)BATCH * NSMP * D2C;
  unsigned short* featB = (unsigned short*)(ws + off); off += (size_t)BN_TOTAL * CIN / 2;
  unsigned short* Y1    = (unsigned short*)(ws + off); off += (size_t)BN_TOTAL * C1 / 2;
  unsigned short* Y2    = (unsigned short*)(ws + off); off += (size_t)BN_TOTAL * C2 / 2;
  unsigned short* W1h   = (unsigned short*)(ws + off); off += (size_t)C1 * CIN / 2;
  unsigned short* W2h   = (unsigned short*)(ws + off); off += (size_t)C2 * C1 / 2;
  float* sposI   = ws + off; off += (size_t)BATCH * NSMP * 3;
  float4* qs4    = (float4*)(ws + off); off += (size_t)BATCH * NSMP * 4;
  float* stats   = ws + off; off += 1024;
  float* sum1   = stats;        // [256]
  float* sumsq1 = stats + 256;  // [256]
  float* sum2   = stats + 512;  // [128]
  float* sumsq2 = stats + 640;  // [128]

  prep_all<<<PT_T + PT_S + PT_M, 256, 0, stream>>>(
      sfeat, sfeatT, skip, featB, spos, sposI, qs4, W1, W1h, W2, W2h, stats);

  knn_all<<<BN_TOTAL / 256, 512, 0, stream>>>(pos, qs4, sposI, sfeatT, featB);

  gemm1_mw<<<dim3(C1 / BM, NRB), 256, 0, stream>>>(
      featB, W1h, b1, Y1, sum1, sumsq1);

  gemm2_mw<<<NRB, 256, 0, stream>>>(
      Y1, g1, beta1, sum1, sumsq1, W2h, b2, Y2, sum2, sumsq2);

  final_kernel<<<dim3(NPT / 32, C2 / 32, BATCH), dim3(32, 8), 0, stream>>>(
      Y2, sum2, sumsq2, g2, beta2, out);
}

// Round 8
// 283.124 us; speedup vs baseline: 2.1247x; 1.0163x over previous
//
#include <hip/hip_runtime.h>

// Problem constants
constexpr int BATCH = 8;
constexpr int NPT   = 8192;   // N points
constexpr int NSMP  = 2048;   // S sampled points
constexpr int D1C   = 128;    // skip feature channels
constexpr int D2C   = 256;    // sampled feature channels
constexpr int CIN   = 384;    // D1C + D2C
constexpr int C1    = 256;    // layer-1 out channels
constexpr int C2    = 128;    // layer-2 out channels
constexpr int BN_TOTAL = BATCH * NPT;  // 65536 rows

// Multi-wave GEMM tiling: 4 waves (256 thr), 128x128 tile, BK=32 (m97 structure)
constexpr int BM = 128, BK = 32;
constexpr int NRB = BN_TOTAL / BM;   // 512 row-blocks

typedef __bf16 bf16x8 __attribute__((ext_vector_type(8)));
typedef short  s16x8  __attribute__((ext_vector_type(8)));
typedef float  f32x4  __attribute__((ext_vector_type(4)));
typedef unsigned short u16x4 __attribute__((ext_vector_type(4)));

__device__ __forceinline__ unsigned short f2bf(float x) {
  unsigned u = __builtin_bit_cast(unsigned, x);
  u += 0x7fffu + ((u >> 16) & 1u);   // round-to-nearest-even
  return (unsigned short)(u >> 16);
}
__device__ __forceinline__ float bf2f(unsigned short h) {
  return __builtin_bit_cast(float, (unsigned)h << 16);
}

// async global -> LDS, 16 B per lane; lds dest wave-uniform base + lane*16
__device__ __forceinline__ void gld_lds16(const void* g, void* l) {
  __builtin_amdgcn_global_load_lds(
      (const __attribute__((address_space(1))) void*)g,
      (__attribute__((address_space(3))) void*)l, 16, 0, 0);
}

// ---------------------------------------------------------------------------
// prep_all: fused transpose(sfeat->sfeatT) + skip->featB + W casts + spos pack
// + BN-stat zeroing. Role selected by block-index range. 5 graph nodes total.
// R5 lesson: NO __threadfence cross-block reductions on CDNA4 (L2 writeback
// storm); BN stats go through device-scope float atomics (G12).
// ---------------------------------------------------------------------------
constexpr int PT_T = (NSMP / 32) * (D2C / 32) * BATCH;  // 4096 transpose blocks
constexpr int PT_S = (NPT / 32) * (D1C / 32) * BATCH;   // 8192 skip blocks
constexpr int PT_M = (C1 * CIN + 255) / 256;            // 384 misc blocks

__global__ __launch_bounds__(256) void prep_all(
    const float* __restrict__ sfeat, float* __restrict__ sfeatT,
    const float* __restrict__ skip, unsigned short* __restrict__ featB,
    const float* __restrict__ spos, float* __restrict__ sposI,
    float4* __restrict__ qs4,
    const float* __restrict__ W1, unsigned short* __restrict__ W1h,
    const float* __restrict__ W2, unsigned short* __restrict__ W2h,
    float* __restrict__ stats) {   // [0..255]=sum1 [256..511]=sumsq1
                                   // [512..639]=sum2 [640..767]=sumsq2
  __shared__ float tile[32][33];
  int bid = blockIdx.x, tid = threadIdx.x;
  int tx = tid & 31, ty = tid >> 5;
  if (bid < PT_T) {
    // transpose sfeat [B, D2C, NSMP] -> sfeatT [B, NSMP, D2C]
    int z = bid >> 9;           // 512 blocks per batch
    int r = bid & 511;
    int c0 = (r & 63) * 32;     // over NSMP
    int r0 = (r >> 6) * 32;     // over D2C
    const float* inb = sfeat + (size_t)z * D2C * NSMP;
    float* outb = sfeatT + (size_t)z * NSMP * D2C;
#pragma unroll
    for (int i = 0; i < 32; i += 8)
      tile[ty + i][tx] = inb[(size_t)(r0 + ty + i) * NSMP + c0 + tx];
    __syncthreads();
#pragma unroll
    for (int i = 0; i < 32; i += 8)
      outb[(size_t)(c0 + ty + i) * D2C + r0 + tx] = tile[tx][ty + i];
  } else if (bid < PT_T + PT_S) {
    // skip [B, D1C, NPT] -> featB[.][0..127] bf16
    int id = bid - PT_T;
    int z = id >> 10;           // 1024 blocks per batch
    int r = id & 1023;
    int n0 = (r & 255) * 32;    // over NPT
    int d0 = (r >> 8) * 32;     // over D1C
#pragma unroll
    for (int i = 0; i < 32; i += 8)
      tile[ty + i][tx] = skip[((size_t)z * D1C + d0 + ty + i) * NPT + n0 + tx];
    __syncthreads();
#pragma unroll
    for (int i = 0; i < 32; i += 8) {
      int n = n0 + ty + i;
      featB[((size_t)z * NPT + n) * CIN + d0 + tx] = f2bf(tile[tx][ty + i]);
    }
  } else {
    int g = (bid - PT_T - PT_S) * 256 + tid;
    if (g < 768) stats[g] = 0.f;
    if (g < C1 * CIN) W1h[g] = f2bf(W1[g]);
    if (g < C2 * C1)  W2h[g] = f2bf(W2[g]);
    if (g < BATCH * NSMP) {
      int b = g >> 11, s = g & (NSMP - 1);
      const float* sp = spos + (size_t)b * 3 * NSMP;
      float x = sp[s], y = sp[NSMP + s], z = sp[2 * NSMP + s];
      sposI[(size_t)g * 3 + 0] = x;
      sposI[(size_t)g * 3 + 1] = y;
      sposI[(size_t)g * 3 + 2] = z;
      qs4[g] = make_float4(-2.f * x, -2.f * y, -2.f * z,
                           fmaf(x, x, fmaf(y, y, z * z)));
    }
  }
}

// ---------------------------------------------------------------------------
// knn_all: scan + certification + in-block exact fp64 fallback + interp.
// R7 lesson: at grid 256 (=CU count) the kernel is 1 block/CU; the phase
// barriers leave the CU idle (Occ 17.6%, VALUBusy 47%, dur unchanged even
// after FETCH dropped 79->10MB). Fix: 512 blocks x 128 points (2 pts/lane),
// ~35.6KB LDS -> 2 blocks/CU co-resident, phases of the two blocks overlap.
// Retained: XCD swizzle (b=blk&7 -> batch slice XCD-L2-resident, R7-proven),
// LDS candidate delivery via broadcast ds_read_b128 (no TA port cost, R4),
// +pp recentering (R2), mk reuse of the wave's dead qs segment.
// ---------------------------------------------------------------------------
constexpr int KWAVES = 8;
constexpr int SEGK = NSMP / KWAVES;  // 256 candidates per wave
constexpr int PPB  = 128;            // points per block

__device__ __forceinline__ void ins_med3(float kf, float& k0, float& k1,
                                         float& k2, float& k3) {
  float o0 = k0, o1 = k1, o2 = k2;
  k0 = fminf(kf, o0);
  k1 = __builtin_amdgcn_fmed3f(kf, o0, o1);
  k2 = __builtin_amdgcn_fmed3f(kf, o1, o2);
  k3 = __builtin_amdgcn_fmed3f(kf, o2, k3);
}

__device__ __forceinline__ bool dless(double d, int i, double D, int I) {
  return d < D || (d == D && i < I);
}
__device__ __forceinline__ void dins3(double d, int i,
                                      double& b0, double& b1, double& b2,
                                      int& i0, int& i1, int& i2) {
  if (dless(d, i, b2, i2)) {
    if (dless(d, i, b1, i1)) {
      b2 = b1; i2 = i1;
      if (dless(d, i, b0, i0)) { b1 = b0; i1 = i0; b0 = d; i0 = i; }
      else                     { b1 = d; i1 = i; }
    } else { b2 = d; i2 = i; }
  }
}

__global__ __launch_bounds__(512, 4) void knn_all(
    const float* __restrict__ pos,    // [B,3,NPT]
    const float4* __restrict__ qs4g,  // [B,NSMP] transformed
    const float* __restrict__ sposI,  // [B,NSMP,3] original (fp64 paths)
    const float* __restrict__ sfeatT, // [B,NSMP,D2C]
    unsigned short* __restrict__ featB) {
  // qs region (32 KB) doubles as mk storage: wave w's mk (2 KB) overwrites
  // its own finished 4 KB candidate segment — no cross-wave hazard.
  __shared__ __align__(16) unsigned char smem[NSMP * 16];
  float4* qs  = (float4*)smem;
  float*  mkf = (float*)smem;
#define MKF(w, sl, m, l) mkf[(w) * 1024 + ((sl) * 2 + (m)) * 64 + (l)]
  __shared__ int   il[PPB][3];            // per-point neighbor idx
  __shared__ float wl[PPB][3];            // per-point weights
  __shared__ int   fl[PPB];               // flagged-point list
  __shared__ int   fcnt;

  int tid = threadIdx.x;
  int wave = tid >> 6, lane = tid & 63;
  int blk = blockIdx.x;
  int b = blk & 7;               // XCD swizzle: batch b -> XCD b
  int n0 = (blk >> 3) * PPB;     // 64 chunks of 128 points per batch

  if (tid == 0) fcnt = 0;

  const float* pb = pos + (size_t)b * 3 * NPT;
  float px[2], py[2], pz[2], pp[2];
#pragma unroll
  for (int m = 0; m < 2; m++) {
    int n = n0 + (m << 6) + lane;
    px[m] = pb[n]; py[m] = pb[NPT + n]; pz[m] = pb[2 * NPT + n];
    pp[m] = fmaf(px[m], px[m], fmaf(py[m], py[m], pz[m] * pz[m]));
  }

  const float INF = __builtin_inff();
  float k0[2], k1[2], k2[2], k3[2];
#pragma unroll
  for (int m = 0; m < 2; m++) { k0[m] = INF; k1[m] = INF; k2[m] = INF; k3[m] = INF; }

  int s0 = wave * SEGK;
  // stage this wave's candidate segment: 4 x (64 lanes x 16 B) = 4 KB
  const float4* qsrc = qs4g + (size_t)b * NSMP;
#pragma unroll
  for (int r = 0; r < 4; r++)
    gld_lds16(&qsrc[s0 + r * 64 + lane], &qs[s0 + r * 64]);
  __syncthreads();

#define KSTEP2(Q, SS)                                                        \
  {                                                                          \
    _Pragma("unroll")                                                        \
    for (int m_ = 0; m_ < 2; m_++) {                                         \
      float tt = (Q).w + pp[m_];  /* recenter: d small near neighbors */     \
      float d_ = fmaf(px[m_], (Q).x,                                         \
                      fmaf(py[m_], (Q).y, fmaf(pz[m_], (Q).z, tt)));         \
      unsigned ki_ = (__builtin_bit_cast(unsigned, d_) & 0xFFFFF800u) |      \
                     (unsigned)(SS);                                         \
      ins_med3(__builtin_bit_cast(float, ki_), k0[m_], k1[m_], k2[m_], k3[m_]); \
    }                                                                        \
  }

  for (int t = 0; t < SEGK; t += 8) {
    float4 qv[8];
#pragma unroll
    for (int u = 0; u < 8; u++) qv[u] = qs[s0 + t + u];  // broadcast ds_read
#pragma unroll
    for (int u = 0; u < 8; u++) KSTEP2(qv[u], s0 + t + u)
  }
#undef KSTEP2

  // write per-wave top-4 into own (dead) segment
#pragma unroll
  for (int m = 0; m < 2; m++) {
    MKF(wave, 0, m, lane) = k0[m];
    MKF(wave, 1, m, lane) = k1[m];
    MKF(wave, 2, m, lane) = k2[m];
    MKF(wave, 3, m, lane) = k3[m];
  }
  __syncthreads();

  // ---- per-point finalize (PPB threads), flag + fp64 weights into LDS ----
  if (tid < PPB) {
    int pm = tid >> 6, pl = tid & 63;
    float K0 = INF, K1 = INF, K2 = INF, K3 = INF;
#pragma unroll
    for (int w = 0; w < KWAVES; w++)
#pragma unroll
      for (int sl = 0; sl < 4; sl++)
        ins_med3(MKF(w, sl, pm, pl), K0, K1, K2, K3);

    int I0 = (int)(__builtin_bit_cast(unsigned, K0) & 0x7FFu);
    int I1 = (int)(__builtin_bit_cast(unsigned, K1) & 0x7FFu);
    int I2 = (int)(__builtin_bit_cast(unsigned, K2) & 0x7FFu);
    float d2m = __builtin_bit_cast(float, __builtin_bit_cast(unsigned, K2) & 0xFFFFF800u);
    float d3m = __builtin_bit_cast(float, __builtin_bit_cast(unsigned, K3) & 0xFFFFF800u);
    bool flag = (d3m - d2m) < 2e-3f * fmaxf(d3m, 0.f) + 1e-5f;
    if (flag) {
      int slot = atomicAdd(&fcnt, 1);
      fl[slot] = tid;
    }
    int n = n0 + tid;
    const float* q = sposI + (size_t)b * 3 * NSMP;
    double pxd = (double)pb[n], pyd = (double)pb[NPT + n], pzd = (double)pb[2 * NPT + n];
    double dd[3]; int II[3] = {I0, I1, I2};
#pragma unroll
    for (int k = 0; k < 3; k++) {
      double dx = pxd - (double)q[3 * II[k]];
      double dy = pyd - (double)q[3 * II[k] + 1];
      double dz = pzd - (double)q[3 * II[k] + 2];
      dd[k] = dx * dx + dy * dy + dz * dz;
    }
    double w0 = 1.0 / (dd[0] + 1e-8);
    double w1 = 1.0 / (dd[1] + 1e-8);
    double w2 = 1.0 / (dd[2] + 1e-8);
    double inv = 1.0 / (w0 + w1 + w2);
    il[tid][0] = I0; il[tid][1] = I1; il[tid][2] = I2;
    wl[tid][0] = (float)(w0 * inv);
    wl[tid][1] = (float)(w1 * inv);
    wl[tid][2] = (float)(w2 * inv);
  }
  __syncthreads();

  // ---- exact fp64 fallback for flagged points, one wave per point ----
  int fc = fcnt;
  for (int t = wave; t < fc; t += KWAVES) {
    int P = fl[t];
    int n = n0 + P;
    double pxd = (double)pb[n], pyd = (double)pb[NPT + n], pzd = (double)pb[2 * NPT + n];
    const float* q = sposI + (size_t)b * 3 * NSMP;
    double b0 = 1e300, b1 = 1e300, b2 = 1e300;
    int i0 = 0x7FFFFFFF, i1 = 0x7FFFFFFF, i2 = 0x7FFFFFFF;
    for (int s = lane; s < NSMP; s += 64) {
      double dx = pxd - (double)q[3 * s];
      double dy = pyd - (double)q[3 * s + 1];
      double dz = pzd - (double)q[3 * s + 2];
      double d = dx * dx + dy * dy + dz * dz;
      dins3(d, s, b0, b1, b2, i0, i1, i2);
    }
#pragma unroll
    for (int m = 1; m < 64; m <<= 1) {
      double o0 = __shfl_xor(b0, m, 64), o1 = __shfl_xor(b1, m, 64), o2 = __shfl_xor(b2, m, 64);
      int    j0 = __shfl_xor(i0, m, 64), j1 = __shfl_xor(i1, m, 64), j2 = __shfl_xor(i2, m, 64);
      dins3(o0, j0, b0, b1, b2, i0, i1, i2);
      dins3(o1, j1, b0, b1, b2, i0, i1, i2);
      dins3(o2, j2, b0, b1, b2, i0, i1, i2);
    }
    if (lane == 0) {
      double w0 = 1.0 / (b0 + 1e-8);
      double w1 = 1.0 / (b1 + 1e-8);
      double w2 = 1.0 / (b2 + 1e-8);
      double inv = 1.0 / (w0 + w1 + w2);
      il[P][0] = i0; il[P][1] = i1; il[P][2] = i2;
      wl[P][0] = (float)(w0 * inv);
      wl[P][1] = (float)(w1 * inv);
      wl[P][2] = (float)(w2 * inv);
    }
  }
  __syncthreads();

  // ---- interp: each wave handles 16 points; lane covers 4 channels ----
  // sfeatT batch slice (2 MB) is XCD-L2-resident thanks to the swizzle.
  const float* base = sfeatT + (size_t)b * NSMP * D2C;
  for (int i = 0; i < 16; i++) {
    int P = (wave << 4) + i;
    int i0 = il[P][0], i1 = il[P][1], i2 = il[P][2];
    float w0 = wl[P][0], w1 = wl[P][1], w2 = wl[P][2];
    float4 v0 = *(const float4*)&base[(size_t)i0 * D2C + (lane << 2)];
    float4 v1 = *(const float4*)&base[(size_t)i1 * D2C + (lane << 2)];
    float4 v2 = *(const float4*)&base[(size_t)i2 * D2C + (lane << 2)];
    u16x4 o;
    o[0] = f2bf(w0 * v0.x + w1 * v1.x + w2 * v2.x);
    o[1] = f2bf(w0 * v0.y + w1 * v1.y + w2 * v2.y);
    o[2] = f2bf(w0 * v0.z + w1 * v1.z + w2 * v2.z);
    o[3] = f2bf(w0 * v0.w + w1 * v1.w + w2 * v2.w);
    *(u16x4*)&featB[((size_t)b * NPT + n0 + P) * CIN + D1C + (lane << 2)] = o;
  }
#undef MKF
}

// ---------------------------------------------------------------------------
// GEMM1, 4-wave 128x128 tile (m97 structure): Y1 = featB @ W1^T + b1.
// BN1 stats via device-scope float atomics (no fence, no extra node).
// ---------------------------------------------------------------------------
__global__ __launch_bounds__(256) void gemm1_mw(
    const unsigned short* __restrict__ featB,  // [BN_TOTAL][CIN] bf16
    const unsigned short* __restrict__ W1h,    // [C1][CIN] bf16
    const float* __restrict__ bias,
    unsigned short* __restrict__ Y1,           // [BN_TOTAL][C1] bf16
    float* __restrict__ sum1,                  // [C1]
    float* __restrict__ sumsq1) {              // [C1]
  __shared__ __align__(16) unsigned short As[BM * BK];  // 8 KB
  __shared__ __align__(16) unsigned short Bs[BM * BK];  // 8 KB
  int tid = threadIdx.x;
  int lane = tid & 63, w = tid >> 6;
  int wr = w >> 1, wc = w & 1;
  int m16 = lane & 15, quad = lane >> 4;
  int cb = blockIdx.x, rb = blockIdx.y;
  int row0 = rb * BM, col0 = cb * BM;
  int srow = lane >> 2, scol8 = (lane & 3) * 8;

  f32x4 acc[4][4];
#pragma unroll
  for (int j = 0; j < 4; j++) {
    float bj = bias[col0 + wc * 64 + j * 16 + m16];
#pragma unroll
    for (int i = 0; i < 4; i++) acc[i][j] = f32x4{bj, bj, bj, bj};
  }

  for (int k0 = 0; k0 < CIN; k0 += BK) {
#pragma unroll
    for (int kq = 0; kq < 2; kq++) {
      int ar = 32 * w + 16 * kq + srow;
      int lb = __builtin_amdgcn_readfirstlane((32 * w + 16 * kq) * BK);
      gld_lds16(&featB[(size_t)(row0 + ar) * CIN + k0 + scol8], &As[lb]);
      gld_lds16(&W1h[(size_t)(col0 + ar) * CIN + k0 + scol8], &Bs[lb]);
    }
    __syncthreads();

    bf16x8 a[4], bb[4];
#pragma unroll
    for (int i = 0; i < 4; i++)
      a[i] = __builtin_bit_cast(bf16x8,
          *(const s16x8*)&As[(wr * 64 + i * 16 + m16) * BK + quad * 8]);
#pragma unroll
    for (int j = 0; j < 4; j++)
      bb[j] = __builtin_bit_cast(bf16x8,
          *(const s16x8*)&Bs[(wc * 64 + j * 16 + m16) * BK + quad * 8]);
#pragma unroll
    for (int i = 0; i < 4; i++)
#pragma unroll
      for (int j = 0; j < 4; j++)
        acc[i][j] = __builtin_amdgcn_mfma_f32_16x16x32_bf16(a[i], bb[j], acc[i][j], 0, 0, 0);
    __syncthreads();
  }

#pragma unroll
  for (int j = 0; j < 4; j++) {
    int col = col0 + wc * 64 + j * 16 + m16;
    float s = 0.f, q = 0.f;
#pragma unroll
    for (int i = 0; i < 4; i++)
#pragma unroll
      for (int r = 0; r < 4; r++) {
        float v = acc[i][j][r];
        Y1[(size_t)(row0 + wr * 64 + i * 16 + quad * 4 + r) * C1 + col] = f2bf(v);
        s += v; q = fmaf(v, v, q);
      }
    s += __shfl_xor(s, 16, 64); s += __shfl_xor(s, 32, 64);
    q += __shfl_xor(q, 16, 64); q += __shfl_xor(q, 32, 64);
    if (quad == 0) {
      atomicAdd(&sum1[col], s);
      atomicAdd(&sumsq1[col], q);
    }
  }
}

// ---------------------------------------------------------------------------
// GEMM2, 4-wave 128x128 tile: X2 = relu(bn1(Y1)) fused in reg-staged A.
// BN1 coefficients computed in-kernel from atomic sums (gemm1 complete by
// stream order). BN2 stats via atomics. grid = NRB.
// ---------------------------------------------------------------------------
__global__ __launch_bounds__(256) void gemm2_mw(
    const unsigned short* __restrict__ Y1,   // [BN_TOTAL][C1] bf16
    const float* __restrict__ g1, const float* __restrict__ beta1,
    const float* __restrict__ sum1, const float* __restrict__ sumsq1,
    const unsigned short* __restrict__ W2h,  // [C2][C1] bf16
    const float* __restrict__ bias,
    unsigned short* __restrict__ Y2,         // [BN_TOTAL][C2] bf16
    float* __restrict__ sum2, float* __restrict__ sumsq2) {
  __shared__ __align__(16) unsigned short As[BM * BK];
  __shared__ __align__(16) unsigned short Bs[BM * BK];
  __shared__ float scs[C1], shs[C1];
  int tid = threadIdx.x;
  int lane = tid & 63, w = tid >> 6;
  int wr = w >> 1, wc = w & 1;
  int m16 = lane & 15, quad = lane >> 4;
  int rb = blockIdx.x;
  int row0 = rb * BM, col0 = 0;
  int srow = lane >> 2, scol8 = (lane & 3) * 8;

  {  // compute BN1 scale/shift for this thread's channel (C1 == blockDim)
    const float invBN = 1.0f / (float)BN_TOTAL;
    float mean = sum1[tid] * invBN;
    float var = sumsq1[tid] * invBN - mean * mean;
    float sc = g1[tid] / sqrtf(var + 1e-5f);
    scs[tid] = sc;
    shs[tid] = beta1[tid] - mean * sc;
  }

  f32x4 acc[4][4];
#pragma unroll
  for (int j = 0; j < 4; j++) {
    float bj = bias[col0 + wc * 64 + j * 16 + m16];
#pragma unroll
    for (int i = 0; i < 4; i++) acc[i][j] = f32x4{bj, bj, bj, bj};
  }
  __syncthreads();

  for (int k0 = 0; k0 < C1; k0 += BK) {
#pragma unroll
    for (int kq = 0; kq < 2; kq++) {
      int ar = 32 * w + 16 * kq + srow;
      int lb = __builtin_amdgcn_readfirstlane((32 * w + 16 * kq) * BK);
      gld_lds16(&W2h[(size_t)(col0 + ar) * C1 + k0 + scol8], &Bs[lb]);
      // A tile: load Y1, apply BN1+ReLU, write LDS
      s16x8 v = *(const s16x8*)&Y1[(size_t)(row0 + ar) * C1 + k0 + scol8];
      unsigned short ov[8];
#pragma unroll
      for (int e = 0; e < 8; e++) {
        float x = bf2f((unsigned short)v[e]);
        float y = fmaxf(fmaf(x, scs[k0 + scol8 + e], shs[k0 + scol8 + e]), 0.f);
        ov[e] = f2bf(y);
      }
      *(s16x8*)&As[ar * BK + scol8] = *(const s16x8*)ov;
    }
    __syncthreads();

    bf16x8 a[4], bb[4];
#pragma unroll
    for (int i = 0; i < 4; i++)
      a[i] = __builtin_bit_cast(bf16x8,
          *(const s16x8*)&As[(wr * 64 + i * 16 + m16) * BK + quad * 8]);
#pragma unroll
    for (int j = 0; j < 4; j++)
      bb[j] = __builtin_bit_cast(bf16x8,
          *(const s16x8*)&Bs[(wc * 64 + j * 16 + m16) * BK + quad * 8]);
#pragma unroll
    for (int i = 0; i < 4; i++)
#pragma unroll
      for (int j = 0; j < 4; j++)
        acc[i][j] = __builtin_amdgcn_mfma_f32_16x16x32_bf16(a[i], bb[j], acc[i][j], 0, 0, 0);
    __syncthreads();
  }

#pragma unroll
  for (int j = 0; j < 4; j++) {
    int col = col0 + wc * 64 + j * 16 + m16;
    float s = 0.f, q = 0.f;
#pragma unroll
    for (int i = 0; i < 4; i++)
#pragma unroll
      for (int r = 0; r < 4; r++) {
        float v = acc[i][j][r];
        Y2[(size_t)(row0 + wr * 64 + i * 16 + quad * 4 + r) * C2 + col] = f2bf(v);
        s += v; q = fmaf(v, v, q);
      }
    s += __shfl_xor(s, 16, 64); s += __shfl_xor(s, 32, 64);
    q += __shfl_xor(q, 16, 64); q += __shfl_xor(q, 32, 64);
    if (quad == 0) {
      atomicAdd(&sum2[col], s);
      atomicAdd(&sumsq2[col], q);
    }
  }
}

// ---------------------------------------------------------------------------
// Final: out[b][c][n] = relu(bn2(Y2)) transposed, fp32 out.
// BN2 coefficients computed inline from atomic sums.
// ---------------------------------------------------------------------------
__global__ void final_kernel(const unsigned short* __restrict__ Y2,
                             const float* __restrict__ sum2,
                             const float* __restrict__ sumsq2,
                             const float* __restrict__ g2,
                             const float* __restrict__ beta2,
                             float* __restrict__ out) {
  __shared__ float tile[32][33];
  int b = blockIdx.z;
  int n0 = blockIdx.x * 32;
  int c0 = blockIdx.y * 32;
  int tx = threadIdx.x, ty = threadIdx.y;
  int c = c0 + tx;
  const float invBN = 1.0f / (float)BN_TOTAL;
  float mean = sum2[c] * invBN;
  float var = sumsq2[c] * invBN - mean * mean;
  float sc = g2[c] / sqrtf(var + 1e-5f);
  float sh = beta2[c] - mean * sc;
#pragma unroll
  for (int i = 0; i < 32; i += 8) {
    int n = n0 + ty + i;
    float v = bf2f(Y2[((size_t)b * NPT + n) * C2 + c0 + tx]);
    tile[ty + i][tx] = fmaxf(fmaf(v, sc, sh), 0.f);
  }
  __syncthreads();
#pragma unroll
  for (int i = 0; i < 32; i += 8) {
    int cc = c0 + ty + i;
    out[((size_t)b * C2 + cc) * NPT + n0 + tx] = tile[tx][ty + i];
  }
}

// ---------------------------------------------------------------------------
extern "C" void kernel_launch(void* const* d_in, const int* in_sizes, int n_in,
                              void* d_out, int out_size, void* d_ws, size_t ws_size,
                              hipStream_t stream) {
  (void)in_sizes; (void)n_in; (void)out_size; (void)ws_size;
  const float* pos   = (const float*)d_in[0];
  const float* spos  = (const float*)d_in[1];
  const float* skip  = (const float*)d_in[2];
  const float* sfeat = (const float*)d_in[3];
  const float* W1    = (const float*)d_in[4];
  const float* b1    = (const float*)d_in[5];
  const float* g1    = (const float*)d_in[6];
  const float* beta1 = (const float*)d_in[7];
  const float* W2    = (const float*)d_in[8];
  const float* b2    = (const float*)d_in[9];
  const float* g2    = (const float*)d_in[10];
  const float* beta2 = (const float*)d_in[11];
  float* out = (float*)d_out;

  float* ws = (float*)d_ws;
  size_t off = 0;
  float* sfeatT  = ws + off; off += (size_t)BATCH * NSMP * D2C;
  unsigned short* featB = (unsigned short*)(ws + off); off += (size_t)BN_TOTAL * CIN / 2;
  unsigned short* Y1    = (unsigned short*)(ws + off); off += (size_t)BN_TOTAL * C1 / 2;
  unsigned short* Y2    = (unsigned short*)(ws + off); off += (size_t)BN_TOTAL * C2 / 2;
  unsigned short* W1h   = (unsigned short*)(ws + off); off += (size_t)C1 * CIN / 2;
  unsigned short* W2h   = (unsigned short*)(ws + off); off += (size_t)C2 * C1 / 2;
  float* sposI   = ws + off; off += (size_t)BATCH * NSMP * 3;
  float4* qs4    = (float4*)(ws + off); off += (size_t)BATCH * NSMP * 4;
  float* stats   = ws + off; off += 1024;
  float* sum1   = stats;        // [256]
  float* sumsq1 = stats + 256;  // [256]
  float* sum2   = stats + 512;  // [128]
  float* sumsq2 = stats + 640;  // [128]

  prep_all<<<PT_T + PT_S + PT_M, 256, 0, stream>>>(
      sfeat, sfeatT, skip, featB, spos, sposI, qs4, W1, W1h, W2, W2h, stats);

  knn_all<<<BN_TOTAL / PPB, 512, 0, stream>>>(pos, qs4, sposI, sfeatT, featB);

  gemm1_mw<<<dim3(C1 / BM, NRB), 256, 0, stream>>>(
      featB, W1h, b1, Y1, sum1, sumsq1);

  gemm2_mw<<<NRB, 256, 0, stream>>>(
      Y1, g1, beta1, sum1, sumsq1, W2h, b2, Y2, sum2, sumsq2);

  final_kernel<<<dim3(NPT / 32, C2 / 32, BATCH), dim3(32, 8), 0, stream>>>(
      Y2, sum2, sumsq2, g2, beta2, out);
}